// Round 1
// 468.724 us; speedup vs baseline: 1.0164x; 1.0164x over previous
//
#include <hip/hip_runtime.h>
#include <hip/hip_bf16.h>
#include <cstdint>
#include <type_traits>

#define D_MODEL 2048
#define NH 16
#define HD 128
#define SEQ 2048
#define QKV_LD (3 * D_MODEL) // 6144

typedef __attribute__((ext_vector_type(8))) short short8;
typedef __attribute__((ext_vector_type(4))) float f32x4;
typedef __attribute__((ext_vector_type(16))) float f32x16;

__device__ __forceinline__ ushort f2bf(float f) {
    union { float f; uint32_t u; } c; c.f = f;
    uint32_t u = c.u;
    uint32_t r = (u + 0x7FFFu + ((u >> 16) & 1u)) >> 16;
    return (ushort)r;
}
__device__ __forceinline__ float bf2f(ushort b) {
    union { uint32_t u; float f; } c; c.u = ((uint32_t)b) << 16;
    return c.f;
}

// async global->LDS, 16B per lane. LDS dest = wave-uniform base + lane*16 (HW).
__device__ __forceinline__ void load_lds16(const ushort* g, ushort* l) {
    __builtin_amdgcn_global_load_lds(
        (const __attribute__((address_space(1))) void*)g,
        (__attribute__((address_space(3))) void*)l, 16, 0, 0);
}

// ---------------- fp32 -> bf16 cast (x) ----------------
__global__ void cvt_bf16_kernel(const float* __restrict__ in, ushort* __restrict__ out, int n4) {
    int idx = blockIdx.x * blockDim.x + threadIdx.x;
    if (idx >= n4) return;
    float4 v = ((const float4*)in)[idx];
    ushort4 o;
    o.x = f2bf(v.x); o.y = f2bf(v.y); o.z = f2bf(v.z); o.w = f2bf(v.w);
    ((ushort4*)out)[idx] = o;
}

// ---------------- fp32 [R][C] -> bf16 [C][R] transpose ----------------
__global__ void transpose_bf16_kernel(const float* __restrict__ in, ushort* __restrict__ out,
                                      int R, int C) {
    __shared__ float tile[32][33];
    int tx = threadIdx.x, ty = threadIdx.y; // 32 x 8
    int c0 = blockIdx.x * 32, r0 = blockIdx.y * 32;
    for (int i = 0; i < 4; ++i) {
        int r = r0 + ty + i * 8;
        tile[ty + i * 8][tx] = in[(size_t)r * C + c0 + tx];
    }
    __syncthreads();
    for (int i = 0; i < 4; ++i) {
        int c = c0 + ty + i * 8;
        out[(size_t)c * R + r0 + tx] = f2bf(tile[tx][ty + i * 8]);
    }
}

// ---------------- bf16 MFMA GEMM: C[M][N] = A[M][K] * Bt[N][K]^T + bias ----------------
// m97 structure: 128^2 tile, BK=32, 4 waves, global_load_lds width=16 staging.
template <typename OutT>
__global__ __launch_bounds__(256) void gemm_bt_bias(
    const ushort* __restrict__ A,   // [M][K] bf16
    const ushort* __restrict__ Bt,  // [N][K] bf16
    const float* __restrict__ bias, // [N]
    OutT* __restrict__ C,           // [M][N] fp32 or bf16
    int M, int N, int K)
{
    __shared__ __align__(16) ushort As[128 * 32];
    __shared__ __align__(16) ushort Bs[128 * 32];
    int t = threadIdx.x;
    int m0 = blockIdx.y * 128, n0 = blockIdx.x * 128;
    int wave = t >> 6, lane = t & 63;
    int wm = (wave & 1) * 64, wn = (wave >> 1) * 64;
    int lr = lane & 15, lh = lane >> 4;

    f32x4 acc[4][4];
    for (int i = 0; i < 4; i++)
        for (int j = 0; j < 4; j++)
            acc[i][j] = (f32x4)0.0f;

    // staging map: thread t sources row (t>>2), k-col (t&3)*8; LDS byte off = t*16 (linear).
    int srow = t >> 2;
    int scol = (t & 3) * 8;
    const ushort* Ag = A + (size_t)(m0 + srow) * K + scol;
    const ushort* Bg = Bt + (size_t)(n0 + srow) * K + scol;
    ushort* AsW = As + wave * 512;  // 1024 B per-wave base
    ushort* BsW = Bs + wave * 512;

    for (int k0 = 0; k0 < K; k0 += 32) {
        __syncthreads();
        load_lds16(Ag + k0, AsW);
        load_lds16(Ag + (size_t)64 * K + k0, AsW + 2048);
        load_lds16(Bg + k0, BsW);
        load_lds16(Bg + (size_t)64 * K + k0, BsW + 2048);
        __syncthreads(); // drains vmcnt(0) -> tile visible
        short8 a[4], b[4];
        for (int i = 0; i < 4; i++)
            a[i] = *(const short8*)(As + (wm + i * 16 + lr) * 32 + lh * 8);
        for (int j = 0; j < 4; j++)
            b[j] = *(const short8*)(Bs + (wn + j * 16 + lr) * 32 + lh * 8);
        for (int i = 0; i < 4; i++)
            for (int j = 0; j < 4; j++)
                acc[i][j] = __builtin_amdgcn_mfma_f32_16x16x32_bf16(a[i], b[j], acc[i][j], 0, 0, 0);
    }

    for (int i = 0; i < 4; i++) {
        int row = m0 + wm + i * 16 + lh * 4;
        for (int j = 0; j < 4; j++) {
            int col = n0 + wn + j * 16 + lr;
            float bv = bias[col];
            for (int r = 0; r < 4; r++) {
                float v = acc[i][j][r] + bv;
                if constexpr (std::is_same<OutT, ushort>::value)
                    C[(size_t)(row + r) * N + col] = f2bf(v);
                else
                    C[(size_t)(row + r) * N + col] = v;
            }
        }
    }
}

// ---------------- RoPE cos/sin table: [s][j] -> (cos, sin), 2048*64 entries ----------------
// Same math as the previous per-element path (powf + sincosf) => bitwise-identical results.
__global__ void rope_table(float2* __restrict__ tab) {
    int i = blockIdx.x * blockDim.x + threadIdx.x; // 0..131071
    int s = i >> 6, j = i & 63;
    float theta = powf(10000.0f, -(float)j * (1.0f / 64.0f));
    float ang = (float)s * theta;
    float sn, cs;
    sincosf(ang, &sn, &cs);
    tab[i] = make_float2(cs, sn);
}

// ---------------- RoPE + cast + reshape: qkv_bf16 -> Qb,Kb [bh][s][128] ----------------
// Q gets pre-scaled by 1/sqrt(HD). One wave per 128-dim head vector. Trig from table.
__global__ void rope_cast_qk(const ushort* __restrict__ qkv,
                             const float2* __restrict__ tab,
                             ushort* __restrict__ Qb, ushort* __restrict__ Kb) {
    int t = threadIdx.x;
    int wv = blockIdx.x * 4 + (t >> 6); // 0..131071
    int j = t & 63;
    int bs = wv >> 5;
    int rem = wv & 31;
    int which = rem >> 4;  // 0=q, 1=k
    int h = rem & 15;
    int s = bs & 2047;
    int b = bs >> 11;
    size_t src = (size_t)bs * QKV_LD + which * D_MODEL + h * HD;
    uint32_t pr = *(const uint32_t*)(qkv + src + 2 * j);
    float x1 = bf2f((ushort)(pr & 0xffff));
    float x2 = bf2f((ushort)(pr >> 16));
    float2 cspair = tab[(s << 6) + j];
    float cs = cspair.x, sn = cspair.y;
    float sc = which ? 1.0f : 0.08838834764831845f; // fold 1/sqrt(128) into Q
    float o1 = (x1 * cs - x2 * sn) * sc;
    float o2 = (x1 * sn + x2 * cs) * sc;
    ushort* dst = which ? Kb : Qb;
    size_t obase = ((size_t)(b * NH + h) * SEQ + s) * HD;
    dst[obase + j] = f2bf(o1);
    dst[obase + 64 + j] = f2bf(o2);
}

// ---------------- V transpose: qkv_bf16 v-part -> Vt [bh][d=128][s=2048] ----------------
__global__ void v_transpose(const ushort* __restrict__ qkv, ushort* __restrict__ Vt) {
    __shared__ ushort tile[32][33];
    int tx = threadIdx.x, ty = threadIdx.y; // 32 x 8
    int s0 = blockIdx.x * 32;
    int d0 = blockIdx.y * 32;
    int bh = blockIdx.z;
    int b = bh >> 4, h = bh & 15;
    for (int i = 0; i < 4; ++i) {
        int s = s0 + ty + i * 8;
        tile[ty + i * 8][tx] = qkv[((size_t)(b * SEQ + s)) * QKV_LD + 2 * D_MODEL + h * HD + d0 + tx];
    }
    __syncthreads();
    for (int i = 0; i < 4; ++i) {
        int d = d0 + ty + i * 8;
        Vt[((size_t)bh * HD + d) * SEQ + s0 + tx] = tile[tx][ty + i * 8];
    }
}

// ---------------- MFMA flash attention ----------------
// Block: 256 thr / 4 waves, q-tile 128 (wave w owns 32 q), key-tile 64, one (b,h).
// S^T = K·Q^T via mfma_32x32x16 => q in lanes, keys in regs => register softmax.
// PV as O^T = V^T·P^T: A-frags = Vt rows, B-frags = P[q][k] rows (both contiguous).
__global__ __launch_bounds__(256) void attn_mfma(const ushort* __restrict__ Qb,
                                                 const ushort* __restrict__ Kb,
                                                 const ushort* __restrict__ Vt,
                                                 ushort* __restrict__ ctx) {
    __shared__ ushort smem[25600]; // Ks[0,8192) Vts[8192,16384) Ps[16384,25600)
    ushort* Ks = smem;          // [64][128], 16B chunks swizzled: c' = c ^ (row&15)
    ushort* Vts = smem + 8192;  // [128][64], 16B chunks swizzled: c' = c ^ (row&7)
    ushort* Ps = smem + 16384;  // [128][72] (pad 8 => 144B rows, 16B aligned)

    int t = threadIdx.x;
    int w = t >> 6, l = t & 63;
    int l31 = l & 31, g = l >> 5;
    int q0 = blockIdx.x * 128;
    int bh = blockIdx.y;
    int b = bh >> 4, h = bh & 15;

    int qrow = q0 + w * 32 + l31;
    const ushort* Qg = Qb + ((size_t)bh * SEQ + qrow) * HD;
    short8 qf[8];
#pragma unroll
    for (int kc = 0; kc < 8; kc++)
        qf[kc] = *(const short8*)(Qg + kc * 16 + g * 8);

    f32x16 O[4];
#pragma unroll
    for (int di = 0; di < 4; di++) O[di] = (f32x16)0.0f;
    float m_run = -INFINITY, l_run = 0.0f;

    const ushort* KgB = Kb + (size_t)bh * SEQ * HD;
    const ushort* VtB = Vt + (size_t)bh * HD * SEQ;

    for (int k0 = 0; k0 < SEQ; k0 += 64) {
        __syncthreads();
        // stage K tile 64x128 (16 KB): 4 x uint4 per thread, swizzled chunks
#pragma unroll
        for (int c2 = 0; c2 < 4; c2++) {
            int f = c2 * 256 + t;
            int r = f >> 4, c = f & 15;
            int cp = c ^ (r & 15);
            uint4 v = *(const uint4*)(KgB + (size_t)(k0 + r) * HD + c * 8);
            *(uint4*)(Ks + r * 128 + cp * 8) = v;
        }
        // stage Vt tile 128x64 (16 KB)
#pragma unroll
        for (int c2 = 0; c2 < 4; c2++) {
            int f = c2 * 256 + t;
            int d = f >> 3, c = f & 7;
            int cp = c ^ (d & 7);
            uint4 v = *(const uint4*)(VtB + (size_t)d * SEQ + k0 + c * 8);
            *(uint4*)(Vts + d * 64 + cp * 8) = v;
        }
        __syncthreads();

        // S^T = K · Q^T : per wave [64 keys][32 q] as 2 tiles of 32x32
        f32x16 St[2];
        St[0] = (f32x16)0.0f;
        St[1] = (f32x16)0.0f;
#pragma unroll
        for (int ki = 0; ki < 2; ki++) {
            int row = ki * 32 + l31;
#pragma unroll
            for (int kc = 0; kc < 8; kc++) {
                int cp = (kc * 2 + g) ^ (row & 15);
                short8 a = *(const short8*)(Ks + row * 128 + cp * 8);
                St[ki] = __builtin_amdgcn_mfma_f32_32x32x16_bf16(a, qf[kc], St[ki], 0, 0, 0);
            }
        }

        // online softmax: this lane's q = q0+w*32+l31; keys live in regs
        float mx = -INFINITY;
#pragma unroll
        for (int ki = 0; ki < 2; ki++)
#pragma unroll
            for (int r = 0; r < 16; r++) mx = fmaxf(mx, St[ki][r]);
        mx = fmaxf(mx, __shfl_xor(mx, 32));
        float mn = fmaxf(m_run, mx);
        float alpha = __expf(m_run - mn);
        m_run = mn;
        float psum = 0.0f;
#pragma unroll
        for (int ki = 0; ki < 2; ki++)
#pragma unroll
            for (int r = 0; r < 16; r++) {
                float p = __expf(St[ki][r] - mn);
                St[ki][r] = p;
                psum += p;
            }
        psum += __shfl_xor(psum, 32);
        l_run = l_run * alpha + psum;
#pragma unroll
        for (int di = 0; di < 4; di++)
#pragma unroll
            for (int r = 0; r < 16; r++) O[di][r] *= alpha;

        // P (bf16) -> LDS, wave-private rows; reg-quads = 4 consecutive keys => b64 writes
        {
            int qloc = w * 32 + l31;
            ushort* Pr = Ps + qloc * 72;
#pragma unroll
            for (int ki = 0; ki < 2; ki++)
#pragma unroll
                for (int u = 0; u < 4; u++) {
                    ushort4 pk;
                    pk.x = f2bf(St[ki][4 * u + 0]);
                    pk.y = f2bf(St[ki][4 * u + 1]);
                    pk.z = f2bf(St[ki][4 * u + 2]);
                    pk.w = f2bf(St[ki][4 * u + 3]);
                    *(ushort4*)(Pr + ki * 32 + 8 * u + 4 * g) = pk;
                }
        }

        // O^T += V^T · P^T : per wave [128 d][32 q] as 4 tiles of 32x32, kk = 64/16 = 4
        {
            int qloc = w * 32 + l31;
            short8 pb[4];
#pragma unroll
            for (int kc = 0; kc < 4; kc++)
                pb[kc] = *(const short8*)(Ps + qloc * 72 + kc * 16 + g * 8);
#pragma unroll
            for (int di = 0; di < 4; di++) {
                int d = di * 32 + l31;
#pragma unroll
                for (int kc = 0; kc < 4; kc++) {
                    int cp = (kc * 2 + g) ^ (d & 7);
                    short8 va = *(const short8*)(Vts + d * 64 + cp * 8);
                    O[di] = __builtin_amdgcn_mfma_f32_32x32x16_bf16(va, pb[kc], O[di], 0, 0, 0);
                }
            }
        }
    }

    // epilogue: normalize, transpose through LDS (reuse Ks/Vts region), coalesced store
    __syncthreads();
    float inv = 1.0f / l_run;
    ushort* ob = smem; // [128][128] rows = block-local q
    {
        int qloc = w * 32 + l31;
        ushort* orow = ob + qloc * 128;
#pragma unroll
        for (int di = 0; di < 4; di++)
#pragma unroll
            for (int u = 0; u < 4; u++) {
                ushort4 pk;
                pk.x = f2bf(O[di][4 * u + 0] * inv);
                pk.y = f2bf(O[di][4 * u + 1] * inv);
                pk.z = f2bf(O[di][4 * u + 2] * inv);
                pk.w = f2bf(O[di][4 * u + 3] * inv);
                *(ushort4*)(orow + di * 32 + 8 * u + 4 * g) = pk;
            }
    }
    // wave-private readback (rows w*32..w*32+31) -> coalesced 256B global rows
#pragma unroll
    for (int p = 0; p < 8; p++) {
        int qloc = w * 32 + p * 4 + (l >> 4);
        int c16 = l & 15;
        uint4 v = *(const uint4*)(ob + qloc * 128 + c16 * 8);
        size_t tok = (size_t)b * SEQ + q0 + qloc;
        *(uint4*)(ctx + tok * D_MODEL + h * HD + c16 * 8) = v;
    }
}

extern "C" void kernel_launch(void* const* d_in, const int* in_sizes, int n_in,
                              void* d_out, int out_size, void* d_ws, size_t ws_size,
                              hipStream_t stream) {
    const float* x    = (const float*)d_in[0];
    const float* Wqkv = (const float*)d_in[1];
    const float* bqkv = (const float*)d_in[2];
    const float* Wo   = (const float*)d_in[3];
    const float* bo   = (const float*)d_in[4];
    float* out = (float*)d_out;

    char* ws = (char*)d_ws;
    ushort* x_bf   = (ushort*)(ws);                  // 16 MB [0,16M)
    ushort* wqkvT  = (ushort*)(ws + 16777216);       // 24 MB
    ushort* woT    = (ushort*)(ws + 41943040);       //  8 MB
    ushort* qkv_bf = (ushort*)(ws + 50331648);       // 48 MB: [4096][6144] bf16
    ushort* Qb     = (ushort*)(ws + 100663296);      // 16 MB: [32][2048][128] bf16
    ushort* Kb     = (ushort*)(ws + 117440512);      // 16 MB
    ushort* VtG    = (ushort*)(ws + 134217728);      // 16 MB: [32][128][2048] bf16
    ushort* ctx    = (ushort*)(ws + 150994944);      // 16 MB -> total 160 MB
    // rope table overlaps ctx region (1 MB): consumed by rope_cast_qk BEFORE attn writes ctx.
    float2* rtab   = (float2*)(ws + 150994944);

    rope_table<<<512, 256, 0, stream>>>(rtab);
    cvt_bf16_kernel<<<8192, 256, 0, stream>>>(x, x_bf, 2097152);
    transpose_bf16_kernel<<<dim3(192, 64), dim3(32, 8), 0, stream>>>(Wqkv, wqkvT, 2048, 6144);
    transpose_bf16_kernel<<<dim3(64, 64), dim3(32, 8), 0, stream>>>(Wo, woT, 2048, 2048);
    // qkv = x @ Wqkv + bqkv  -> bf16
    gemm_bt_bias<ushort><<<dim3(48, 32), 256, 0, stream>>>(x_bf, wqkvT, bqkv, qkv_bf, 4096, 6144, 2048);
    // RoPE + reshape q,k ; transpose v
    rope_cast_qk<<<32768, 256, 0, stream>>>(qkv_bf, rtab, Qb, Kb);
    v_transpose<<<dim3(64, 4, 32), dim3(32, 8), 0, stream>>>(qkv_bf, VtG);
    // MFMA flash attention -> ctx bf16
    attn_mfma<<<dim3(16, 32), 256, 0, stream>>>(Qb, Kb, VtG, ctx);
    // out = ctx @ Wo + bo
    gemm_bt_bias<float><<<dim3(16, 32), 256, 0, stream>>>(ctx, woT, bo, out, 4096, 2048, 2048);
}

// Round 2
// 450.496 us; speedup vs baseline: 1.0575x; 1.0405x over previous
//
#include <hip/hip_runtime.h>
#include <hip/hip_bf16.h>
#include <cstdint>
#include <type_traits>

#define D_MODEL 2048
#define NH 16
#define HD 128
#define SEQ 2048
#define QKV_LD (3 * D_MODEL) // 6144

typedef __attribute__((ext_vector_type(8))) short short8;
typedef __attribute__((ext_vector_type(4))) float f32x4;
typedef __attribute__((ext_vector_type(16))) float f32x16;

__device__ __forceinline__ ushort f2bf(float f) {
    union { float f; uint32_t u; } c; c.f = f;
    uint32_t u = c.u;
    uint32_t r = (u + 0x7FFFu + ((u >> 16) & 1u)) >> 16;
    return (ushort)r;
}
__device__ __forceinline__ float bf2f(ushort b) {
    union { uint32_t u; float f; } c; c.u = ((uint32_t)b) << 16;
    return c.f;
}

// async global->LDS, 16B per lane. LDS dest = wave-uniform base + lane*16 (HW).
__device__ __forceinline__ void load_lds16(const ushort* g, ushort* l) {
    __builtin_amdgcn_global_load_lds(
        (const __attribute__((address_space(1))) void*)g,
        (__attribute__((address_space(3))) void*)l, 16, 0, 0);
}

// ---------------- fp32 -> bf16 cast (x) ----------------
__global__ void cvt_bf16_kernel(const float* __restrict__ in, ushort* __restrict__ out, int n4) {
    int idx = blockIdx.x * blockDim.x + threadIdx.x;
    if (idx >= n4) return;
    float4 v = ((const float4*)in)[idx];
    ushort4 o;
    o.x = f2bf(v.x); o.y = f2bf(v.y); o.z = f2bf(v.z); o.w = f2bf(v.w);
    ((ushort4*)out)[idx] = o;
}

// ---------------- fp32 [R][C] -> bf16 [C][R] transpose ----------------
__global__ void transpose_bf16_kernel(const float* __restrict__ in, ushort* __restrict__ out,
                                      int R, int C) {
    __shared__ float tile[32][33];
    int tx = threadIdx.x, ty = threadIdx.y; // 32 x 8
    int c0 = blockIdx.x * 32, r0 = blockIdx.y * 32;
    for (int i = 0; i < 4; ++i) {
        int r = r0 + ty + i * 8;
        tile[ty + i * 8][tx] = in[(size_t)r * C + c0 + tx];
    }
    __syncthreads();
    for (int i = 0; i < 4; ++i) {
        int c = c0 + ty + i * 8;
        out[(size_t)c * R + r0 + tx] = f2bf(tile[tx][ty + i * 8]);
    }
}

// ================= 256x256 8-phase bf16 GEMM (HK-style template) =================
// C[M][N] = A[M][K] * Bt[N][K]^T + bias. BK=64, 8 waves (2Mx4N), dbuf LDS 128 KiB.
// LDS tile [256][64] bf16, row=128B=8 chunks of 16B; logical chunk c of row r lives
// at physical chunk c^(r&7). global_load_lds dest is linear; source is pre-swizzled.
// Per K-tile: 4 phases (quadrants (mh,nh)=(0,0),(0,1),(1,0),(1,1)), each
// {ds_reads; 2 stage issues; barrier; setprio1; 16 MFMA; setprio0; barrier}.
// Counted vmcnt(2) once per K-tile boundary (A0/A2 of T+2 stay in flight).
#define STAGE_A(L, T_, B_) load_lds16(Ag + (size_t)(L) * 64 * K + (size_t)(T_) * 64, \
                                      smA + (B_) * 16384 + (L) * 4096 + ldsW)
#define STAGE_B(L, T_, B_) load_lds16(Bg + (size_t)(L) * 64 * K + (size_t)(T_) * 64, \
                                      smB + (B_) * 16384 + (L) * 4096 + ldsW)
#define READ_A(MH) do { const ushort* _ab = smA + cb * 16384 + aRow + (MH) * 4096; \
    _Pragma("unroll") for (int i_ = 0; i_ < 4; ++i_) { \
        af[i_][0] = *(const short8*)(_ab + i_ * 1024 + pc0); \
        af[i_][1] = *(const short8*)(_ab + i_ * 1024 + pc1); } } while (0)
#define READ_B(NHh) do { const ushort* _bb = smB + cb * 16384 + bRow + (NHh) * 2048; \
    _Pragma("unroll") for (int j_ = 0; j_ < 2; ++j_) { \
        bfr[j_][0] = *(const short8*)(_bb + j_ * 1024 + pc0); \
        bfr[j_][1] = *(const short8*)(_bb + j_ * 1024 + pc1); } } while (0)
#define MFMA16(MH, NHh) do { \
    _Pragma("unroll") for (int i_ = 0; i_ < 4; ++i_) \
    _Pragma("unroll") for (int j_ = 0; j_ < 2; ++j_) { \
        acc[(MH) * 4 + i_][(NHh) * 2 + j_] = __builtin_amdgcn_mfma_f32_16x16x32_bf16( \
            af[i_][0], bfr[j_][0], acc[(MH) * 4 + i_][(NHh) * 2 + j_], 0, 0, 0); \
        acc[(MH) * 4 + i_][(NHh) * 2 + j_] = __builtin_amdgcn_mfma_f32_16x16x32_bf16( \
            af[i_][1], bfr[j_][1], acc[(MH) * 4 + i_][(NHh) * 2 + j_], 0, 0, 0); } } while (0)

template <typename OutT>
__global__ __launch_bounds__(512, 2) void gemm256(
    const ushort* __restrict__ A,   // [M][K] bf16
    const ushort* __restrict__ Bt,  // [N][K] bf16
    const float* __restrict__ bias, // [N]
    OutT* __restrict__ C,           // [M][N]
    int M, int N, int K)
{
    __shared__ __align__(16) ushort sm[65536]; // 128 KiB: A dbuf 64K, B dbuf 64K
    ushort* smA = sm;
    ushort* smB = sm + 32768;

    int t = threadIdx.x;
    int w = t >> 6, lane = t & 63;
    int lr = lane & 15, lh = lane >> 4;     // frag row sel / k-chunk sel
    int wm_idx = w >> 2, wn_idx = w & 3;    // 2 x 4 wave grid
    int m0 = blockIdx.y * 256, n0 = blockIdx.x * 256;

    // staging: thread t fills LDS bytes [L*8192 + t*16); row = 64L + t/8, phys chunk = t&7
    // -> global logical chunk = (t&7) ^ ((t/8)&7)
    int srow = t >> 3;
    int scol = ((t & 7) ^ (srow & 7)) << 3;
    const ushort* Ag = A + (size_t)(m0 + srow) * K + scol;
    const ushort* Bg = Bt + (size_t)(n0 + srow) * K + scol;
    int ldsW = w * 512; // wave-uniform LDS slice (ushort units)

    // ds_read: row & 7 == lr & 7 for every fragment row -> per-lane constant swizzle
    int pc0 = (lh ^ (lr & 7)) << 3;
    int pc1 = ((4 + lh) ^ (lr & 7)) << 3;
    int aRow = (wm_idx * 128 + lr) * 64;
    int bRow = (wn_idx * 64 + lr) * 64;

    f32x4 acc[8][4];
#pragma unroll
    for (int i = 0; i < 8; ++i)
#pragma unroll
        for (int j = 0; j < 4; ++j) acc[i][j] = (f32x4)0.0f;
    short8 af[4][2], bfr[2][2];

    int NT = K >> 6;

    // prologue: all of K-tile 0, plus A0/A2 of K-tile 1 in flight
    STAGE_A(0, 0, 0); STAGE_A(1, 0, 0); STAGE_A(2, 0, 0); STAGE_A(3, 0, 0);
    STAGE_B(0, 0, 0); STAGE_B(1, 0, 0); STAGE_B(2, 0, 0); STAGE_B(3, 0, 0);
    if (NT > 1) {
        STAGE_A(0, 1, 1); STAGE_A(2, 1, 1);
        asm volatile("s_waitcnt vmcnt(2)" ::: "memory");
    } else {
        asm volatile("s_waitcnt vmcnt(0)" ::: "memory");
    }
    __builtin_amdgcn_s_barrier();
    __builtin_amdgcn_sched_barrier(0);

    for (int T = 0; T < NT; ++T) {
        int cb = T & 1, nb = cb ^ 1;
        // ---- phase 1: quadrant (0,0); issue A1,A3 of T+1 ----
        READ_A(0); READ_B(0);
        if (T + 1 < NT) { STAGE_A(1, T + 1, nb); STAGE_A(3, T + 1, nb); }
        __builtin_amdgcn_s_barrier();
        __builtin_amdgcn_s_setprio(1); MFMA16(0, 0); __builtin_amdgcn_s_setprio(0);
        __builtin_amdgcn_s_barrier();
        // ---- phase 2: quadrant (0,1); issue B0,B1 of T+1 ----
        READ_B(1);
        if (T + 1 < NT) { STAGE_B(0, T + 1, nb); STAGE_B(1, T + 1, nb); }
        __builtin_amdgcn_s_barrier();
        __builtin_amdgcn_s_setprio(1); MFMA16(0, 1); __builtin_amdgcn_s_setprio(0);
        __builtin_amdgcn_s_barrier();
        // ---- phase 3: quadrant (1,0); issue B2,B3 of T+1 and A0,A2 of T+2 ----
        // (A-L0/A-L2 of buf cb are dead after phase 2 -> WAR-safe behind the barrier)
        READ_A(1); READ_B(0);
        if (T + 1 < NT) { STAGE_B(2, T + 1, nb); STAGE_B(3, T + 1, nb); }
        if (T + 2 < NT) { STAGE_A(0, T + 2, cb); STAGE_A(2, T + 2, cb); }
        __builtin_amdgcn_s_barrier();
        __builtin_amdgcn_s_setprio(1); MFMA16(1, 0); __builtin_amdgcn_s_setprio(0);
        __builtin_amdgcn_s_barrier();
        // ---- phase 4: quadrant (1,1); K-tile boundary vmcnt ----
        READ_B(1);
        __builtin_amdgcn_s_barrier();
        __builtin_amdgcn_s_setprio(1); MFMA16(1, 1); __builtin_amdgcn_s_setprio(0);
        if (T + 2 < NT) asm volatile("s_waitcnt vmcnt(2)" ::: "memory"); // A0/A2(T+2) stay in flight
        else            asm volatile("s_waitcnt vmcnt(0)" ::: "memory"); // tail drain
        __builtin_amdgcn_s_barrier();
        __builtin_amdgcn_sched_barrier(0);
    }

    // epilogue: direct global store from acc
    float bv[4];
#pragma unroll
    for (int jj = 0; jj < 4; ++jj) bv[jj] = bias[n0 + wn_idx * 64 + jj * 16 + lr];
#pragma unroll
    for (int ii = 0; ii < 8; ++ii) {
        int row = m0 + wm_idx * 128 + ii * 16 + lh * 4;
#pragma unroll
        for (int jj = 0; jj < 4; ++jj) {
            int col = n0 + wn_idx * 64 + jj * 16 + lr;
#pragma unroll
            for (int r = 0; r < 4; ++r) {
                float v = acc[ii][jj][r] + bv[jj];
                if constexpr (std::is_same<OutT, ushort>::value)
                    C[(size_t)(row + r) * N + col] = f2bf(v);
                else
                    C[(size_t)(row + r) * N + col] = v;
            }
        }
    }
}

// ---------------- RoPE cos/sin table: [s][j] -> (cos, sin), 2048*64 entries ----------------
__global__ void rope_table(float2* __restrict__ tab) {
    int i = blockIdx.x * blockDim.x + threadIdx.x; // 0..131071
    int s = i >> 6, j = i & 63;
    float theta = powf(10000.0f, -(float)j * (1.0f / 64.0f));
    float ang = (float)s * theta;
    float sn, cs;
    sincosf(ang, &sn, &cs);
    tab[i] = make_float2(cs, sn);
}

// ---------------- RoPE + cast + reshape: qkv_bf16 -> Qb,Kb [bh][s][128] ----------------
__global__ void rope_cast_qk(const ushort* __restrict__ qkv,
                             const float2* __restrict__ tab,
                             ushort* __restrict__ Qb, ushort* __restrict__ Kb) {
    int t = threadIdx.x;
    int wv = blockIdx.x * 4 + (t >> 6); // 0..131071
    int j = t & 63;
    int bs = wv >> 5;
    int rem = wv & 31;
    int which = rem >> 4;  // 0=q, 1=k
    int h = rem & 15;
    int s = bs & 2047;
    int b = bs >> 11;
    size_t src = (size_t)bs * QKV_LD + which * D_MODEL + h * HD;
    uint32_t pr = *(const uint32_t*)(qkv + src + 2 * j);
    float x1 = bf2f((ushort)(pr & 0xffff));
    float x2 = bf2f((ushort)(pr >> 16));
    float2 cspair = tab[(s << 6) + j];
    float cs = cspair.x, sn = cspair.y;
    float sc = which ? 1.0f : 0.08838834764831845f; // fold 1/sqrt(128) into Q
    float o1 = (x1 * cs - x2 * sn) * sc;
    float o2 = (x1 * sn + x2 * cs) * sc;
    ushort* dst = which ? Kb : Qb;
    size_t obase = ((size_t)(b * NH + h) * SEQ + s) * HD;
    dst[obase + j] = f2bf(o1);
    dst[obase + 64 + j] = f2bf(o2);
}

// ---------------- V transpose: qkv_bf16 v-part -> Vt [bh][d=128][s=2048] ----------------
__global__ void v_transpose(const ushort* __restrict__ qkv, ushort* __restrict__ Vt) {
    __shared__ ushort tile[32][33];
    int tx = threadIdx.x, ty = threadIdx.y; // 32 x 8
    int s0 = blockIdx.x * 32;
    int d0 = blockIdx.y * 32;
    int bh = blockIdx.z;
    int b = bh >> 4, h = bh & 15;
    for (int i = 0; i < 4; ++i) {
        int s = s0 + ty + i * 8;
        tile[ty + i * 8][tx] = qkv[((size_t)(b * SEQ + s)) * QKV_LD + 2 * D_MODEL + h * HD + d0 + tx];
    }
    __syncthreads();
    for (int i = 0; i < 4; ++i) {
        int d = d0 + ty + i * 8;
        Vt[((size_t)bh * HD + d) * SEQ + s0 + tx] = tile[tx][ty + i * 8];
    }
}

// ---------------- MFMA flash attention ----------------
__global__ __launch_bounds__(256) void attn_mfma(const ushort* __restrict__ Qb,
                                                 const ushort* __restrict__ Kb,
                                                 const ushort* __restrict__ Vt,
                                                 ushort* __restrict__ ctx) {
    __shared__ ushort smem[25600]; // Ks[0,8192) Vts[8192,16384) Ps[16384,25600)
    ushort* Ks = smem;          // [64][128], 16B chunks swizzled: c' = c ^ (row&15)
    ushort* Vts = smem + 8192;  // [128][64], 16B chunks swizzled: c' = c ^ (row&7)
    ushort* Ps = smem + 16384;  // [128][72] (pad 8 => 144B rows, 16B aligned)

    int t = threadIdx.x;
    int w = t >> 6, l = t & 63;
    int l31 = l & 31, g = l >> 5;
    int q0 = blockIdx.x * 128;
    int bh = blockIdx.y;
    int b = bh >> 4, h = bh & 15;

    int qrow = q0 + w * 32 + l31;
    const ushort* Qg = Qb + ((size_t)bh * SEQ + qrow) * HD;
    short8 qf[8];
#pragma unroll
    for (int kc = 0; kc < 8; kc++)
        qf[kc] = *(const short8*)(Qg + kc * 16 + g * 8);

    f32x16 O[4];
#pragma unroll
    for (int di = 0; di < 4; di++) O[di] = (f32x16)0.0f;
    float m_run = -INFINITY, l_run = 0.0f;

    const ushort* KgB = Kb + (size_t)bh * SEQ * HD;
    const ushort* VtB = Vt + (size_t)bh * HD * SEQ;

    for (int k0 = 0; k0 < SEQ; k0 += 64) {
        __syncthreads();
#pragma unroll
        for (int c2 = 0; c2 < 4; c2++) {
            int f = c2 * 256 + t;
            int r = f >> 4, c = f & 15;
            int cp = c ^ (r & 15);
            uint4 v = *(const uint4*)(KgB + (size_t)(k0 + r) * HD + c * 8);
            *(uint4*)(Ks + r * 128 + cp * 8) = v;
        }
#pragma unroll
        for (int c2 = 0; c2 < 4; c2++) {
            int f = c2 * 256 + t;
            int d = f >> 3, c = f & 7;
            int cp = c ^ (d & 7);
            uint4 v = *(const uint4*)(VtB + (size_t)d * SEQ + k0 + c * 8);
            *(uint4*)(Vts + d * 64 + cp * 8) = v;
        }
        __syncthreads();

        f32x16 St[2];
        St[0] = (f32x16)0.0f;
        St[1] = (f32x16)0.0f;
#pragma unroll
        for (int ki = 0; ki < 2; ki++) {
            int row = ki * 32 + l31;
#pragma unroll
            for (int kc = 0; kc < 8; kc++) {
                int cp = (kc * 2 + g) ^ (row & 15);
                short8 a = *(const short8*)(Ks + row * 128 + cp * 8);
                St[ki] = __builtin_amdgcn_mfma_f32_32x32x16_bf16(a, qf[kc], St[ki], 0, 0, 0);
            }
        }

        float mx = -INFINITY;
#pragma unroll
        for (int ki = 0; ki < 2; ki++)
#pragma unroll
            for (int r = 0; r < 16; r++) mx = fmaxf(mx, St[ki][r]);
        mx = fmaxf(mx, __shfl_xor(mx, 32));
        float mn = fmaxf(m_run, mx);
        float alpha = __expf(m_run - mn);
        m_run = mn;
        float psum = 0.0f;
#pragma unroll
        for (int ki = 0; ki < 2; ki++)
#pragma unroll
            for (int r = 0; r < 16; r++) {
                float p = __expf(St[ki][r] - mn);
                St[ki][r] = p;
                psum += p;
            }
        psum += __shfl_xor(psum, 32);
        l_run = l_run * alpha + psum;
#pragma unroll
        for (int di = 0; di < 4; di++)
#pragma unroll
            for (int r = 0; r < 16; r++) O[di][r] *= alpha;

        {
            int qloc = w * 32 + l31;
            ushort* Pr = Ps + qloc * 72;
#pragma unroll
            for (int ki = 0; ki < 2; ki++)
#pragma unroll
                for (int u = 0; u < 4; u++) {
                    ushort4 pk;
                    pk.x = f2bf(St[ki][4 * u + 0]);
                    pk.y = f2bf(St[ki][4 * u + 1]);
                    pk.z = f2bf(St[ki][4 * u + 2]);
                    pk.w = f2bf(St[ki][4 * u + 3]);
                    *(ushort4*)(Pr + ki * 32 + 8 * u + 4 * g) = pk;
                }
        }

        {
            int qloc = w * 32 + l31;
            short8 pb[4];
#pragma unroll
            for (int kc = 0; kc < 4; kc++)
                pb[kc] = *(const short8*)(Ps + qloc * 72 + kc * 16 + g * 8);
#pragma unroll
            for (int di = 0; di < 4; di++) {
                int d = di * 32 + l31;
#pragma unroll
                for (int kc = 0; kc < 4; kc++) {
                    int cp = (kc * 2 + g) ^ (d & 7);
                    short8 va = *(const short8*)(Vts + d * 64 + cp * 8);
                    O[di] = __builtin_amdgcn_mfma_f32_32x32x16_bf16(va, pb[kc], O[di], 0, 0, 0);
                }
            }
        }
    }

    __syncthreads();
    float inv = 1.0f / l_run;
    ushort* ob = smem; // [128][128] rows = block-local q
    {
        int qloc = w * 32 + l31;
        ushort* orow = ob + qloc * 128;
#pragma unroll
        for (int di = 0; di < 4; di++)
#pragma unroll
            for (int u = 0; u < 4; u++) {
                ushort4 pk;
                pk.x = f2bf(O[di][4 * u + 0] * inv);
                pk.y = f2bf(O[di][4 * u + 1] * inv);
                pk.z = f2bf(O[di][4 * u + 2] * inv);
                pk.w = f2bf(O[di][4 * u + 3] * inv);
                *(ushort4*)(orow + di * 32 + 8 * u + 4 * g) = pk;
            }
    }
#pragma unroll
    for (int p = 0; p < 8; p++) {
        int qloc = w * 32 + p * 4 + (l >> 4);
        int c16 = l & 15;
        uint4 v = *(const uint4*)(ob + qloc * 128 + c16 * 8);
        size_t tok = (size_t)b * SEQ + q0 + qloc;
        *(uint4*)(ctx + tok * D_MODEL + h * HD + c16 * 8) = v;
    }
}

extern "C" void kernel_launch(void* const* d_in, const int* in_sizes, int n_in,
                              void* d_out, int out_size, void* d_ws, size_t ws_size,
                              hipStream_t stream) {
    const float* x    = (const float*)d_in[0];
    const float* Wqkv = (const float*)d_in[1];
    const float* bqkv = (const float*)d_in[2];
    const float* Wo   = (const float*)d_in[3];
    const float* bo   = (const float*)d_in[4];
    float* out = (float*)d_out;

    char* ws = (char*)d_ws;
    ushort* x_bf   = (ushort*)(ws);                  // 16 MB [0,16M)
    ushort* wqkvT  = (ushort*)(ws + 16777216);       // 24 MB
    ushort* woT    = (ushort*)(ws + 41943040);       //  8 MB
    ushort* qkv_bf = (ushort*)(ws + 50331648);       // 48 MB: [4096][6144] bf16
    ushort* Qb     = (ushort*)(ws + 100663296);      // 16 MB: [32][2048][128] bf16
    ushort* Kb     = (ushort*)(ws + 117440512);      // 16 MB
    ushort* VtG    = (ushort*)(ws + 134217728);      // 16 MB: [32][128][2048] bf16
    ushort* ctx    = (ushort*)(ws + 150994944);      // 16 MB -> total 160 MB
    // rope table overlaps ctx region (1 MB): consumed by rope_cast_qk BEFORE attn writes ctx.
    float2* rtab   = (float2*)(ws + 150994944);

    rope_table<<<512, 256, 0, stream>>>(rtab);
    cvt_bf16_kernel<<<8192, 256, 0, stream>>>(x, x_bf, 2097152);
    transpose_bf16_kernel<<<dim3(192, 64), dim3(32, 8), 0, stream>>>(Wqkv, wqkvT, 2048, 6144);
    transpose_bf16_kernel<<<dim3(64, 64), dim3(32, 8), 0, stream>>>(Wo, woT, 2048, 2048);
    // qkv = x @ Wqkv + bqkv  -> bf16 (256^2 8-phase)
    gemm256<ushort><<<dim3(24, 16), 512, 0, stream>>>(x_bf, wqkvT, bqkv, qkv_bf, 4096, 6144, 2048);
    // RoPE + reshape q,k ; transpose v
    rope_cast_qk<<<32768, 256, 0, stream>>>(qkv_bf, rtab, Qb, Kb);
    v_transpose<<<dim3(64, 4, 32), dim3(32, 8), 0, stream>>>(qkv_bf, VtG);
    // MFMA flash attention -> ctx bf16
    attn_mfma<<<dim3(16, 32), 256, 0, stream>>>(Qb, Kb, VtG, ctx);
    // out = ctx @ Wo + bo (256^2 8-phase)
    gemm256<float><<<dim3(8, 16), 512, 0, stream>>>(ctx, woT, bo, out, 4096, 2048, 2048);
}

// Round 3
// 447.231 us; speedup vs baseline: 1.0652x; 1.0073x over previous
//
#include <hip/hip_runtime.h>
#include <hip/hip_bf16.h>
#include <cstdint>
#include <type_traits>

#define D_MODEL 2048
#define NH 16
#define HD 128
#define SEQ 2048
#define QKV_LD (3 * D_MODEL) // 6144

typedef __attribute__((ext_vector_type(8))) short short8;
typedef __attribute__((ext_vector_type(4))) float f32x4;
typedef __attribute__((ext_vector_type(16))) float f32x16;

__device__ __forceinline__ ushort f2bf(float f) {
    union { float f; uint32_t u; } c; c.f = f;
    uint32_t u = c.u;
    uint32_t r = (u + 0x7FFFu + ((u >> 16) & 1u)) >> 16;
    return (ushort)r;
}
__device__ __forceinline__ float bf2f(ushort b) {
    union { uint32_t u; float f; } c; c.u = ((uint32_t)b) << 16;
    return c.f;
}

// async global->LDS, 16B per lane. LDS dest = wave-uniform base + lane*16 (HW).
__device__ __forceinline__ void load_lds16(const ushort* g, ushort* l) {
    __builtin_amdgcn_global_load_lds(
        (const __attribute__((address_space(1))) void*)g,
        (__attribute__((address_space(3))) void*)l, 16, 0, 0);
}

// ---------------- fp32 -> bf16 cast (x) ----------------
__global__ void cvt_bf16_kernel(const float* __restrict__ in, ushort* __restrict__ out, int n4) {
    int idx = blockIdx.x * blockDim.x + threadIdx.x;
    if (idx >= n4) return;
    float4 v = ((const float4*)in)[idx];
    ushort4 o;
    o.x = f2bf(v.x); o.y = f2bf(v.y); o.z = f2bf(v.z); o.w = f2bf(v.w);
    ((ushort4*)out)[idx] = o;
}

// ---------------- fp32 [R][C] -> bf16 [C][R] transpose ----------------
__global__ void transpose_bf16_kernel(const float* __restrict__ in, ushort* __restrict__ out,
                                      int R, int C) {
    __shared__ float tile[32][33];
    int tx = threadIdx.x, ty = threadIdx.y; // 32 x 8
    int c0 = blockIdx.x * 32, r0 = blockIdx.y * 32;
    for (int i = 0; i < 4; ++i) {
        int r = r0 + ty + i * 8;
        tile[ty + i * 8][tx] = in[(size_t)r * C + c0 + tx];
    }
    __syncthreads();
    for (int i = 0; i < 4; ++i) {
        int c = c0 + ty + i * 8;
        out[(size_t)c * R + r0 + tx] = f2bf(tile[tx][ty + i * 8]);
    }
}

// ================= 256x256 8-phase bf16 GEMM =================
// C[M][N] = A[M][K] * Bt[N][K]^T + bias. BK=64, 8 waves (2Mx4N), dbuf LDS 128 KiB.
// LDS tiles [256][64] bf16; 16B chunks XOR-swizzled: phys chunk = logical ^ (row&7),
// achieved with linear global_load_lds dest + pre-swizzled global source.
// B rows stored NHh-major: LDS p-row = NHh*128 + wn*32 + (r&31); maps each 8KB load
// unit to exactly one consuming phase.
// Quadrant order (0,0),(0,1),(1,1),(1,0): B NHh=1 fragment reused P2->P3.
// Issue schedule (tile T, all into buf nb for T+1): P1:{A0,A2,B0,B1} P2:{B2,B3} P3:{A1,A3}.
// Every load has a 4-phase lead. Counted waits: end-P1 vmcnt(6), end-P2 vmcnt(6),
// end-P4 vmcnt(4); never below 4 outstanding in steady state.
#define WAITV(N) asm volatile("s_waitcnt vmcnt(" #N ")" ::: "memory")
#define LGKM0()  do { asm volatile("s_waitcnt lgkmcnt(0)" ::: "memory"); \
                      __builtin_amdgcn_sched_barrier(0); } while (0)
#define BAR()    do { __builtin_amdgcn_s_barrier(); \
                      __builtin_amdgcn_sched_barrier(0); } while (0)

#define STAGE_A(L, T_, B_) load_lds16(Ag + (size_t)(L) * 64 * K + (size_t)(T_) * 64, \
                                      smA + (B_) * 16384 + (L) * 4096 + ldsW)
// B global row offset for load-unit L: (L&1)*128 + (L>>1)*32
#define STAGE_B(L, T_, B_) load_lds16(Bg + (size_t)(((L) & 1) * 128 + ((L) >> 1) * 32) * K + (size_t)(T_) * 64, \
                                      smB + (B_) * 16384 + (L) * 4096 + ldsW)
#define READ_A(MH) do { const ushort* _ab = smA + cb * 16384 + aRow + (MH) * 4096; \
    _Pragma("unroll") for (int i_ = 0; i_ < 4; ++i_) { \
        af[i_][0] = *(const short8*)(_ab + i_ * 1024 + pc0); \
        af[i_][1] = *(const short8*)(_ab + i_ * 1024 + pc1); } } while (0)
#define READ_B(NHh) do { const ushort* _bb = smB + cb * 16384 + (NHh) * 8192 + bRow; \
    _Pragma("unroll") for (int j_ = 0; j_ < 2; ++j_) { \
        bfr[j_][0] = *(const short8*)(_bb + j_ * 1024 + pc0); \
        bfr[j_][1] = *(const short8*)(_bb + j_ * 1024 + pc1); } } while (0)
#define MFMA16(MH, NHh) do { \
    _Pragma("unroll") for (int i_ = 0; i_ < 4; ++i_) \
    _Pragma("unroll") for (int j_ = 0; j_ < 2; ++j_) { \
        acc[(MH) * 4 + i_][(NHh) * 2 + j_] = __builtin_amdgcn_mfma_f32_16x16x32_bf16( \
            af[i_][0], bfr[j_][0], acc[(MH) * 4 + i_][(NHh) * 2 + j_], 0, 0, 0); \
        acc[(MH) * 4 + i_][(NHh) * 2 + j_] = __builtin_amdgcn_mfma_f32_16x16x32_bf16( \
            af[i_][1], bfr[j_][1], acc[(MH) * 4 + i_][(NHh) * 2 + j_], 0, 0, 0); } } while (0)

template <typename OutT>
__global__ __launch_bounds__(512, 2) void gemm256(
    const ushort* __restrict__ A,   // [M][K] bf16
    const ushort* __restrict__ Bt,  // [N][K] bf16
    const float* __restrict__ bias, // [N]
    OutT* __restrict__ C,           // [M][N]
    int M, int N, int K)
{
    __shared__ __align__(16) ushort sm[65536]; // 128 KiB: A dbuf 64K, B dbuf 64K
    ushort* smA = sm;
    ushort* smB = sm + 32768;

    int t = threadIdx.x;
    int w = t >> 6, lane = t & 63;
    int lr = lane & 15, lh = lane >> 4;     // frag row sel / k-chunk sel
    int wm_idx = w >> 2, wn_idx = w & 3;    // 2 x 4 wave grid
    int m0 = blockIdx.y * 256, n0 = blockIdx.x * 256;

    // staging: thread t fills LDS bytes [tilebase + t*16); tile-row = t/8, phys chunk = t&7
    // -> global logical chunk = (t&7) ^ ((t/8)&7)
    int srow = t >> 3;
    int scol = ((t & 7) ^ (srow & 7)) << 3;
    const ushort* Ag = A + (size_t)(m0 + srow) * K + scol;
    // B row permutation: LDS p-row -> global row (srow>>5)*64 + (srow&31) (+ per-L offset)
    int bq = (srow >> 5) * 64 + (srow & 31);
    const ushort* Bg = Bt + (size_t)(n0 + bq) * K + scol;
    int ldsW = w * 512; // wave-uniform LDS slice (ushort units)

    // ds_read: row & 7 == lr & 7 for every fragment row -> per-lane constant swizzle
    int pc0 = (lh ^ (lr & 7)) << 3;
    int pc1 = ((4 + lh) ^ (lr & 7)) << 3;
    int aRow = (wm_idx * 128 + lr) * 64;
    int bRow = (wn_idx * 32 + lr) * 64; // NHh-major permuted B layout

    f32x4 acc[8][4];
#pragma unroll
    for (int i = 0; i < 8; ++i)
#pragma unroll
        for (int j = 0; j < 4; ++j) acc[i][j] = (f32x4)0.0f;
    short8 af[4][2], bfr[2][2];

    int NT = K >> 6;

    // prologue: tile 0 in FIFO order {A0,A2,B0,B1}{B2,B3}{A1,A3}; keep last 4 in flight
    STAGE_A(0, 0, 0); STAGE_A(2, 0, 0); STAGE_B(0, 0, 0); STAGE_B(1, 0, 0);
    STAGE_B(2, 0, 0); STAGE_B(3, 0, 0);
    STAGE_A(1, 0, 0); STAGE_A(3, 0, 0);
    WAITV(4);
    BAR();

    for (int T = 0; T < NT; ++T) {
        int cb = T & 1, nb = cb ^ 1;
        bool pf = (T + 1 < NT);
        // ---- P1: quad (0,0) ----
        READ_A(0); READ_B(0);
        if (pf) { STAGE_A(0, T + 1, nb); STAGE_A(2, T + 1, nb);
                  STAGE_B(0, T + 1, nb); STAGE_B(1, T + 1, nb); }
        BAR(); LGKM0();
        __builtin_amdgcn_s_setprio(1); MFMA16(0, 0); __builtin_amdgcn_s_setprio(0);
        if (pf) WAITV(6); else WAITV(2);
        BAR();
        // ---- P2: quad (0,1) ----
        READ_B(1);
        if (pf) { STAGE_B(2, T + 1, nb); STAGE_B(3, T + 1, nb); }
        BAR(); LGKM0();
        __builtin_amdgcn_s_setprio(1); MFMA16(0, 1); __builtin_amdgcn_s_setprio(0);
        if (pf) WAITV(6); else WAITV(0);
        BAR();
        // ---- P3: quad (1,1), reuse bfr (NHh=1) ----
        READ_A(1);
        if (pf) { STAGE_A(1, T + 1, nb); STAGE_A(3, T + 1, nb); }
        BAR(); LGKM0();
        __builtin_amdgcn_s_setprio(1); MFMA16(1, 1); __builtin_amdgcn_s_setprio(0);
        BAR();
        // ---- P4: quad (1,0), re-read B NHh=0 ----
        READ_B(0);
        BAR(); LGKM0();
        __builtin_amdgcn_s_setprio(1); MFMA16(1, 0); __builtin_amdgcn_s_setprio(0);
        WAITV(4);
        BAR();
    }

    // epilogue: direct global store from acc
    float bv[4];
#pragma unroll
    for (int jj = 0; jj < 4; ++jj) bv[jj] = bias[n0 + wn_idx * 64 + jj * 16 + lr];
#pragma unroll
    for (int ii = 0; ii < 8; ++ii) {
        int row = m0 + wm_idx * 128 + ii * 16 + lh * 4;
#pragma unroll
        for (int jj = 0; jj < 4; ++jj) {
            int col = n0 + wn_idx * 64 + jj * 16 + lr;
#pragma unroll
            for (int r = 0; r < 4; ++r) {
                float v = acc[ii][jj][r] + bv[jj];
                if constexpr (std::is_same<OutT, ushort>::value)
                    C[(size_t)(row + r) * N + col] = f2bf(v);
                else
                    C[(size_t)(row + r) * N + col] = v;
            }
        }
    }
}

// ---------------- RoPE cos/sin table: [s][j] -> (cos, sin), 2048*64 entries ----------------
__global__ void rope_table(float2* __restrict__ tab) {
    int i = blockIdx.x * blockDim.x + threadIdx.x; // 0..131071
    int s = i >> 6, j = i & 63;
    float theta = powf(10000.0f, -(float)j * (1.0f / 64.0f));
    float ang = (float)s * theta;
    float sn, cs;
    sincosf(ang, &sn, &cs);
    tab[i] = make_float2(cs, sn);
}

// ---------------- RoPE + cast + reshape: qkv_bf16 -> Qb,Kb [bh][s][128] ----------------
__global__ void rope_cast_qk(const ushort* __restrict__ qkv,
                             const float2* __restrict__ tab,
                             ushort* __restrict__ Qb, ushort* __restrict__ Kb) {
    int t = threadIdx.x;
    int wv = blockIdx.x * 4 + (t >> 6); // 0..131071
    int j = t & 63;
    int bs = wv >> 5;
    int rem = wv & 31;
    int which = rem >> 4;  // 0=q, 1=k
    int h = rem & 15;
    int s = bs & 2047;
    int b = bs >> 11;
    size_t src = (size_t)bs * QKV_LD + which * D_MODEL + h * HD;
    uint32_t pr = *(const uint32_t*)(qkv + src + 2 * j);
    float x1 = bf2f((ushort)(pr & 0xffff));
    float x2 = bf2f((ushort)(pr >> 16));
    float2 cspair = tab[(s << 6) + j];
    float cs = cspair.x, sn = cspair.y;
    float sc = which ? 1.0f : 0.08838834764831845f; // fold 1/sqrt(128) into Q
    float o1 = (x1 * cs - x2 * sn) * sc;
    float o2 = (x1 * sn + x2 * cs) * sc;
    ushort* dst = which ? Kb : Qb;
    size_t obase = ((size_t)(b * NH + h) * SEQ + s) * HD;
    dst[obase + j] = f2bf(o1);
    dst[obase + 64 + j] = f2bf(o2);
}

// ---------------- V transpose: qkv_bf16 v-part -> Vt [bh][d=128][s=2048] ----------------
__global__ void v_transpose(const ushort* __restrict__ qkv, ushort* __restrict__ Vt) {
    __shared__ ushort tile[32][33];
    int tx = threadIdx.x, ty = threadIdx.y; // 32 x 8
    int s0 = blockIdx.x * 32;
    int d0 = blockIdx.y * 32;
    int bh = blockIdx.z;
    int b = bh >> 4, h = bh & 15;
    for (int i = 0; i < 4; ++i) {
        int s = s0 + ty + i * 8;
        tile[ty + i * 8][tx] = qkv[((size_t)(b * SEQ + s)) * QKV_LD + 2 * D_MODEL + h * HD + d0 + tx];
    }
    __syncthreads();
    for (int i = 0; i < 4; ++i) {
        int d = d0 + ty + i * 8;
        Vt[((size_t)bh * HD + d) * SEQ + s0 + tx] = tile[tx][ty + i * 8];
    }
}

// ---------------- MFMA flash attention ----------------
__global__ __launch_bounds__(256) void attn_mfma(const ushort* __restrict__ Qb,
                                                 const ushort* __restrict__ Kb,
                                                 const ushort* __restrict__ Vt,
                                                 ushort* __restrict__ ctx) {
    __shared__ ushort smem[25600]; // Ks[0,8192) Vts[8192,16384) Ps[16384,25600)
    ushort* Ks = smem;          // [64][128], 16B chunks swizzled: c' = c ^ (row&15)
    ushort* Vts = smem + 8192;  // [128][64], 16B chunks swizzled: c' = c ^ (row&7)
    ushort* Ps = smem + 16384;  // [128][72] (pad 8 => 144B rows, 16B aligned)

    int t = threadIdx.x;
    int w = t >> 6, l = t & 63;
    int l31 = l & 31, g = l >> 5;
    int q0 = blockIdx.x * 128;
    int bh = blockIdx.y;
    int b = bh >> 4, h = bh & 15;

    int qrow = q0 + w * 32 + l31;
    const ushort* Qg = Qb + ((size_t)bh * SEQ + qrow) * HD;
    short8 qf[8];
#pragma unroll
    for (int kc = 0; kc < 8; kc++)
        qf[kc] = *(const short8*)(Qg + kc * 16 + g * 8);

    f32x16 O[4];
#pragma unroll
    for (int di = 0; di < 4; di++) O[di] = (f32x16)0.0f;
    float m_run = -INFINITY, l_run = 0.0f;

    const ushort* KgB = Kb + (size_t)bh * SEQ * HD;
    const ushort* VtB = Vt + (size_t)bh * HD * SEQ;

    for (int k0 = 0; k0 < SEQ; k0 += 64) {
        __syncthreads();
#pragma unroll
        for (int c2 = 0; c2 < 4; c2++) {
            int f = c2 * 256 + t;
            int r = f >> 4, c = f & 15;
            int cp = c ^ (r & 15);
            uint4 v = *(const uint4*)(KgB + (size_t)(k0 + r) * HD + c * 8);
            *(uint4*)(Ks + r * 128 + cp * 8) = v;
        }
#pragma unroll
        for (int c2 = 0; c2 < 4; c2++) {
            int f = c2 * 256 + t;
            int d = f >> 3, c = f & 7;
            int cp = c ^ (d & 7);
            uint4 v = *(const uint4*)(VtB + (size_t)d * SEQ + k0 + c * 8);
            *(uint4*)(Vts + d * 64 + cp * 8) = v;
        }
        __syncthreads();

        f32x16 St[2];
        St[0] = (f32x16)0.0f;
        St[1] = (f32x16)0.0f;
#pragma unroll
        for (int ki = 0; ki < 2; ki++) {
            int row = ki * 32 + l31;
#pragma unroll
            for (int kc = 0; kc < 8; kc++) {
                int cp = (kc * 2 + g) ^ (row & 15);
                short8 a = *(const short8*)(Ks + row * 128 + cp * 8);
                St[ki] = __builtin_amdgcn_mfma_f32_32x32x16_bf16(a, qf[kc], St[ki], 0, 0, 0);
            }
        }

        float mx = -INFINITY;
#pragma unroll
        for (int ki = 0; ki < 2; ki++)
#pragma unroll
            for (int r = 0; r < 16; r++) mx = fmaxf(mx, St[ki][r]);
        mx = fmaxf(mx, __shfl_xor(mx, 32));
        float mn = fmaxf(m_run, mx);
        float alpha = __expf(m_run - mn);
        m_run = mn;
        float psum = 0.0f;
#pragma unroll
        for (int ki = 0; ki < 2; ki++)
#pragma unroll
            for (int r = 0; r < 16; r++) {
                float p = __expf(St[ki][r] - mn);
                St[ki][r] = p;
                psum += p;
            }
        psum += __shfl_xor(psum, 32);
        l_run = l_run * alpha + psum;
#pragma unroll
        for (int di = 0; di < 4; di++)
#pragma unroll
            for (int r = 0; r < 16; r++) O[di][r] *= alpha;

        {
            int qloc = w * 32 + l31;
            ushort* Pr = Ps + qloc * 72;
#pragma unroll
            for (int ki = 0; ki < 2; ki++)
#pragma unroll
                for (int u = 0; u < 4; u++) {
                    ushort4 pk;
                    pk.x = f2bf(St[ki][4 * u + 0]);
                    pk.y = f2bf(St[ki][4 * u + 1]);
                    pk.z = f2bf(St[ki][4 * u + 2]);
                    pk.w = f2bf(St[ki][4 * u + 3]);
                    *(ushort4*)(Pr + ki * 32 + 8 * u + 4 * g) = pk;
                }
        }

        {
            int qloc = w * 32 + l31;
            short8 pb[4];
#pragma unroll
            for (int kc = 0; kc < 4; kc++)
                pb[kc] = *(const short8*)(Ps + qloc * 72 + kc * 16 + g * 8);
#pragma unroll
            for (int di = 0; di < 4; di++) {
                int d = di * 32 + l31;
#pragma unroll
                for (int kc = 0; kc < 4; kc++) {
                    int cp = (kc * 2 + g) ^ (d & 7);
                    short8 va = *(const short8*)(Vts + d * 64 + cp * 8);
                    O[di] = __builtin_amdgcn_mfma_f32_32x32x16_bf16(va, pb[kc], O[di], 0, 0, 0);
                }
            }
        }
    }

    __syncthreads();
    float inv = 1.0f / l_run;
    ushort* ob = smem; // [128][128] rows = block-local q
    {
        int qloc = w * 32 + l31;
        ushort* orow = ob + qloc * 128;
#pragma unroll
        for (int di = 0; di < 4; di++)
#pragma unroll
            for (int u = 0; u < 4; u++) {
                ushort4 pk;
                pk.x = f2bf(O[di][4 * u + 0] * inv);
                pk.y = f2bf(O[di][4 * u + 1] * inv);
                pk.z = f2bf(O[di][4 * u + 2] * inv);
                pk.w = f2bf(O[di][4 * u + 3] * inv);
                *(ushort4*)(orow + di * 32 + 8 * u + 4 * g) = pk;
            }
    }
#pragma unroll
    for (int p = 0; p < 8; p++) {
        int qloc = w * 32 + p * 4 + (l >> 4);
        int c16 = l & 15;
        uint4 v = *(const uint4*)(ob + qloc * 128 + c16 * 8);
        size_t tok = (size_t)b * SEQ + q0 + qloc;
        *(uint4*)(ctx + tok * D_MODEL + h * HD + c16 * 8) = v;
    }
}

extern "C" void kernel_launch(void* const* d_in, const int* in_sizes, int n_in,
                              void* d_out, int out_size, void* d_ws, size_t ws_size,
                              hipStream_t stream) {
    const float* x    = (const float*)d_in[0];
    const float* Wqkv = (const float*)d_in[1];
    const float* bqkv = (const float*)d_in[2];
    const float* Wo   = (const float*)d_in[3];
    const float* bo   = (const float*)d_in[4];
    float* out = (float*)d_out;

    char* ws = (char*)d_ws;
    ushort* x_bf   = (ushort*)(ws);                  // 16 MB [0,16M)
    ushort* wqkvT  = (ushort*)(ws + 16777216);       // 24 MB
    ushort* woT    = (ushort*)(ws + 41943040);       //  8 MB
    ushort* qkv_bf = (ushort*)(ws + 50331648);       // 48 MB: [4096][6144] bf16
    ushort* Qb     = (ushort*)(ws + 100663296);      // 16 MB: [32][2048][128] bf16
    ushort* Kb     = (ushort*)(ws + 117440512);      // 16 MB
    ushort* VtG    = (ushort*)(ws + 134217728);      // 16 MB: [32][128][2048] bf16
    ushort* ctx    = (ushort*)(ws + 150994944);      // 16 MB -> total 160 MB
    // rope table overlaps ctx region (1 MB): consumed by rope_cast_qk BEFORE attn writes ctx.
    float2* rtab   = (float2*)(ws + 150994944);

    rope_table<<<512, 256, 0, stream>>>(rtab);
    cvt_bf16_kernel<<<8192, 256, 0, stream>>>(x, x_bf, 2097152);
    transpose_bf16_kernel<<<dim3(192, 64), dim3(32, 8), 0, stream>>>(Wqkv, wqkvT, 2048, 6144);
    transpose_bf16_kernel<<<dim3(64, 64), dim3(32, 8), 0, stream>>>(Wo, woT, 2048, 2048);
    // qkv = x @ Wqkv + bqkv  -> bf16 (256^2 8-phase)
    gemm256<ushort><<<dim3(24, 16), 512, 0, stream>>>(x_bf, wqkvT, bqkv, qkv_bf, 4096, 6144, 2048);
    // RoPE + reshape q,k ; transpose v
    rope_cast_qk<<<32768, 256, 0, stream>>>(qkv_bf, rtab, Qb, Kb);
    v_transpose<<<dim3(64, 4, 32), dim3(32, 8), 0, stream>>>(qkv_bf, VtG);
    // MFMA flash attention -> ctx bf16
    attn_mfma<<<dim3(16, 32), 256, 0, stream>>>(Qb, Kb, VtG, ctx);
    // out = ctx @ Wo + bo (256^2 8-phase)
    gemm256<float><<<dim3(8, 16), 512, 0, stream>>>(ctx, woT, bo, out, 4096, 2048, 2048);
}

// Round 4
// 430.614 us; speedup vs baseline: 1.1063x; 1.0386x over previous
//
#include <hip/hip_runtime.h>
#include <hip/hip_bf16.h>
#include <cstdint>
#include <type_traits>

#define D_MODEL 2048
#define NH 16
#define HD 128
#define SEQ 2048
#define QKV_LD (3 * D_MODEL) // 6144

typedef __attribute__((ext_vector_type(8))) short short8;
typedef __attribute__((ext_vector_type(4))) float f32x4;
typedef __attribute__((ext_vector_type(16))) float f32x16;

__device__ __forceinline__ ushort f2bf(float f) {
    union { float f; uint32_t u; } c; c.f = f;
    uint32_t u = c.u;
    uint32_t r = (u + 0x7FFFu + ((u >> 16) & 1u)) >> 16;
    return (ushort)r;
}
__device__ __forceinline__ float bf2f(ushort b) {
    union { uint32_t u; float f; } c; c.u = ((uint32_t)b) << 16;
    return c.f;
}

// async global->LDS, 16B per lane. LDS dest = wave-uniform base + lane*16 (HW).
__device__ __forceinline__ void load_lds16(const ushort* g, ushort* l) {
    __builtin_amdgcn_global_load_lds(
        (const __attribute__((address_space(1))) void*)g,
        (__attribute__((address_space(3))) void*)l, 16, 0, 0);
}

// ---------------- fp32 -> bf16 cast (x) ----------------
__global__ void cvt_bf16_kernel(const float* __restrict__ in, ushort* __restrict__ out, int n4) {
    int idx = blockIdx.x * blockDim.x + threadIdx.x;
    if (idx >= n4) return;
    float4 v = ((const float4*)in)[idx];
    ushort4 o;
    o.x = f2bf(v.x); o.y = f2bf(v.y); o.z = f2bf(v.z); o.w = f2bf(v.w);
    ((ushort4*)out)[idx] = o;
}

// ---------------- fp32 [R][C] -> bf16 [C][R] transpose ----------------
__global__ void transpose_bf16_kernel(const float* __restrict__ in, ushort* __restrict__ out,
                                      int R, int C) {
    __shared__ float tile[32][33];
    int tx = threadIdx.x, ty = threadIdx.y; // 32 x 8
    int c0 = blockIdx.x * 32, r0 = blockIdx.y * 32;
    for (int i = 0; i < 4; ++i) {
        int r = r0 + ty + i * 8;
        tile[ty + i * 8][tx] = in[(size_t)r * C + c0 + tx];
    }
    __syncthreads();
    for (int i = 0; i < 4; ++i) {
        int c = c0 + ty + i * 8;
        out[(size_t)c * R + r0 + tx] = f2bf(tile[tx][ty + i * 8]);
    }
}

// ================= 256 x (128*NHALF) pipelined bf16 GEMM =================
// C[M][N] = A[M][K] * Bt[N][K]^T + bias. BK=64, 8 waves (2M x 4N).
// LDS XOR-swizzle: 16B chunk c of row r at phys chunk c^(r&7); linear
// global_load_lds dest + pre-swizzled global source; swizzled ds_read.
// NHALF=2 (BN=256): B rows NHh-major-permuted; quadrant order (0,0),(0,1),(1,1),(1,0);
//   both B halves cached in regs (bf0 lives P1->P4, bf1 P2->P3) => 24 ds_reads/K-tile;
//   P3+P4 merged (P4 has no reads). Counted vmcnt: 6/6/4 steady, 2/0 tail.
// NHALF=1 (BN=128): 2 phases; B cached whole tile; vmcnt 3/2 steady, 0 tail.
// No sched_barrier / forced lgkmcnt(0): compiler emits fine-grained lgkm waits so
// early MFMAs overlap remaining ds_reads. Compiler-only fences keep phase ordering.
#define WAITV(N) asm volatile("s_waitcnt vmcnt(" #N ")" ::: "memory")
#define BARF()   do { __builtin_amdgcn_s_barrier(); \
                      asm volatile("" ::: "memory"); } while (0)
#define PRIO1    __builtin_amdgcn_s_setprio(1)
#define PRIO0    __builtin_amdgcn_s_setprio(0)

#define B_ROWOFF(L) (NHALF == 2 ? (((L) & 1) * 128 + ((L) >> 1) * 32) : ((L) * 64))
#define STAGE_A(L, T_, B_) load_lds16(Ag + (size_t)(L) * 64 * K + (size_t)(T_) * 64, \
                                      smA + (B_) * 16384 + (L) * 4096 + ldsW)
#define STAGE_B(L, T_, B_) load_lds16(Bg + (size_t)B_ROWOFF(L) * K + (size_t)(T_) * 64, \
                                      smB + (B_) * (8192 * NHALF) + (L) * 4096 + ldsW)
#define READ_A(MH) do { const ushort* _ab = smA + cb * 16384 + aRow + (MH) * 4096; \
    _Pragma("unroll") for (int i_ = 0; i_ < 4; ++i_) { \
        af[i_][0] = *(const short8*)(_ab + i_ * 1024 + pc0); \
        af[i_][1] = *(const short8*)(_ab + i_ * 1024 + pc1); } } while (0)
#define READ_BH(dst, NHh) do { const ushort* _bb = smB + cb * (8192 * NHALF) + (NHh) * 8192 + bRow; \
    _Pragma("unroll") for (int j_ = 0; j_ < 2; ++j_) { \
        dst[j_][0] = *(const short8*)(_bb + j_ * 1024 + pc0); \
        dst[j_][1] = *(const short8*)(_bb + j_ * 1024 + pc1); } } while (0)
#define MFMA_PH(MH, NHh, bf) do { \
    _Pragma("unroll") for (int i_ = 0; i_ < 4; ++i_) \
    _Pragma("unroll") for (int j_ = 0; j_ < 2; ++j_) { \
        acc[(MH) * 4 + i_][(NHh) * 2 + j_] = __builtin_amdgcn_mfma_f32_16x16x32_bf16( \
            af[i_][0], bf[j_][0], acc[(MH) * 4 + i_][(NHh) * 2 + j_], 0, 0, 0); \
        acc[(MH) * 4 + i_][(NHh) * 2 + j_] = __builtin_amdgcn_mfma_f32_16x16x32_bf16( \
            af[i_][1], bf[j_][1], acc[(MH) * 4 + i_][(NHh) * 2 + j_], 0, 0, 0); } } while (0)

template <typename OutT, int NHALF>
__global__ __launch_bounds__(512, 2) void gemm256(
    const ushort* __restrict__ A,   // [M][K] bf16
    const ushort* __restrict__ Bt,  // [N][K] bf16
    const float* __restrict__ bias, // [N]
    OutT* __restrict__ C,           // [M][N]
    int M, int N, int K)
{
    __shared__ __align__(16) ushort sm[32768 + 2 * 8192 * NHALF];
    ushort* smA = sm;
    ushort* smB = sm + 32768;

    int t = threadIdx.x;
    int w = t >> 6, lane = t & 63;
    int lr = lane & 15, lh = lane >> 4;     // frag row sel / k-chunk sel
    int wm_idx = w >> 2, wn_idx = w & 3;    // 2 x 4 wave grid
    int m0 = blockIdx.y * 256, n0 = blockIdx.x * (128 * NHALF);

    // staging: thread t fills LDS bytes [unit + t*16); row = t/8, phys chunk = t&7
    int srow = t >> 3;
    int scol = ((t & 7) ^ (srow & 7)) << 3;
    const ushort* Ag = A + (size_t)(m0 + srow) * K + scol;
    int bq = (NHALF == 2) ? ((srow >> 5) * 64 + (srow & 31)) : srow;
    const ushort* Bg = Bt + (size_t)(n0 + bq) * K + scol;
    int ldsW = w * 512; // wave-uniform LDS slice (ushort units)

    int pc0 = (lh ^ (lr & 7)) << 3;
    int pc1 = ((4 + lh) ^ (lr & 7)) << 3;
    int aRow = (wm_idx * 128 + lr) * 64;
    int bRow = (wn_idx * 32 + lr) * 64;

    f32x4 acc[8][2 * NHALF];
#pragma unroll
    for (int i = 0; i < 8; ++i)
#pragma unroll
        for (int j = 0; j < 2 * NHALF; ++j) acc[i][j] = (f32x4)0.0f;
    short8 af[4][2], bf0[2][2], bf1[2][2];

    int NT = K >> 6;

    // prologue (FIFO order matters for the counted waits)
    if constexpr (NHALF == 2) {
        STAGE_A(0, 0, 0); STAGE_A(2, 0, 0); STAGE_B(0, 0, 0); STAGE_B(1, 0, 0);
        STAGE_B(2, 0, 0); STAGE_B(3, 0, 0);
        STAGE_A(1, 0, 0); STAGE_A(3, 0, 0);
        WAITV(4);
    } else {
        STAGE_A(0, 0, 0); STAGE_A(2, 0, 0); STAGE_B(0, 0, 0);
        STAGE_B(1, 0, 0); STAGE_A(1, 0, 0); STAGE_A(3, 0, 0);
        WAITV(2);
    }
    BARF();

    for (int T = 0; T < NT; ++T) {
        int cb = T & 1, nb = cb ^ 1;
        bool pf = (T + 1 < NT);
        if constexpr (NHALF == 2) {
            // ---- P1: quad (0,0) ----
            READ_A(0); READ_BH(bf0, 0);
            if (pf) { STAGE_A(0, T + 1, nb); STAGE_A(2, T + 1, nb);
                      STAGE_B(0, T + 1, nb); STAGE_B(1, T + 1, nb); }
            BARF();
            PRIO1; MFMA_PH(0, 0, bf0); PRIO0;
            if (pf) WAITV(6); else WAITV(2);
            BARF();
            // ---- P2: quad (0,1) ----
            READ_BH(bf1, 1);
            if (pf) { STAGE_B(2, T + 1, nb); STAGE_B(3, T + 1, nb); }
            BARF();
            PRIO1; MFMA_PH(0, 1, bf1); PRIO0;
            if (pf) WAITV(6); else WAITV(0);
            BARF();
            // ---- P3+P4: quads (1,1) then (1,0); bf0 cached from P1, no reads for P4 ----
            READ_A(1);
            if (pf) { STAGE_A(1, T + 1, nb); STAGE_A(3, T + 1, nb); }
            BARF();
            PRIO1; MFMA_PH(1, 1, bf1); MFMA_PH(1, 0, bf0); PRIO0;
            if (pf) WAITV(4);
            BARF();
        } else {
            // ---- P1: A-half0 x B ----
            READ_A(0); READ_BH(bf0, 0);
            if (pf) { STAGE_A(0, T + 1, nb); STAGE_A(2, T + 1, nb); STAGE_B(0, T + 1, nb); }
            BARF();
            PRIO1; MFMA_PH(0, 0, bf0); PRIO0;
            if (pf) WAITV(3); else WAITV(0);
            BARF();
            // ---- P2: A-half1 x B (cached) ----
            READ_A(1);
            if (pf) { STAGE_B(1, T + 1, nb); STAGE_A(1, T + 1, nb); STAGE_A(3, T + 1, nb); }
            BARF();
            PRIO1; MFMA_PH(1, 0, bf0); PRIO0;
            if (pf) WAITV(2);
            BARF();
        }
    }

    // epilogue: direct global store from acc
    float bv[2 * NHALF];
#pragma unroll
    for (int jj = 0; jj < 2 * NHALF; ++jj) bv[jj] = bias[n0 + wn_idx * 32 * NHALF + jj * 16 + lr];
#pragma unroll
    for (int ii = 0; ii < 8; ++ii) {
        int row = m0 + wm_idx * 128 + ii * 16 + lh * 4;
#pragma unroll
        for (int jj = 0; jj < 2 * NHALF; ++jj) {
            int col = n0 + wn_idx * 32 * NHALF + jj * 16 + lr;
#pragma unroll
            for (int r = 0; r < 4; ++r) {
                float v = acc[ii][jj][r] + bv[jj];
                if constexpr (std::is_same<OutT, ushort>::value)
                    C[(size_t)(row + r) * N + col] = f2bf(v);
                else
                    C[(size_t)(row + r) * N + col] = v;
            }
        }
    }
}

// ---------------- RoPE cos/sin table: [s][j] -> (cos, sin), 2048*64 entries ----------------
__global__ void rope_table(float2* __restrict__ tab) {
    int i = blockIdx.x * blockDim.x + threadIdx.x; // 0..131071
    int s = i >> 6, j = i & 63;
    float theta = powf(10000.0f, -(float)j * (1.0f / 64.0f));
    float ang = (float)s * theta;
    float sn, cs;
    sincosf(ang, &sn, &cs);
    tab[i] = make_float2(cs, sn);
}

// ---------------- RoPE + cast + reshape: qkv_bf16 -> Qb,Kb [bh][s][128] ----------------
__global__ void rope_cast_qk(const ushort* __restrict__ qkv,
                             const float2* __restrict__ tab,
                             ushort* __restrict__ Qb, ushort* __restrict__ Kb) {
    int t = threadIdx.x;
    int wv = blockIdx.x * 4 + (t >> 6); // 0..131071
    int j = t & 63;
    int bs = wv >> 5;
    int rem = wv & 31;
    int which = rem >> 4;  // 0=q, 1=k
    int h = rem & 15;
    int s = bs & 2047;
    int b = bs >> 11;
    size_t src = (size_t)bs * QKV_LD + which * D_MODEL + h * HD;
    uint32_t pr = *(const uint32_t*)(qkv + src + 2 * j);
    float x1 = bf2f((ushort)(pr & 0xffff));
    float x2 = bf2f((ushort)(pr >> 16));
    float2 cspair = tab[(s << 6) + j];
    float cs = cspair.x, sn = cspair.y;
    float sc = which ? 1.0f : 0.08838834764831845f; // fold 1/sqrt(128) into Q
    float o1 = (x1 * cs - x2 * sn) * sc;
    float o2 = (x1 * sn + x2 * cs) * sc;
    ushort* dst = which ? Kb : Qb;
    size_t obase = ((size_t)(b * NH + h) * SEQ + s) * HD;
    dst[obase + j] = f2bf(o1);
    dst[obase + 64 + j] = f2bf(o2);
}

// ---------------- V transpose: qkv_bf16 v-part -> Vt [bh][d=128][s=2048] ----------------
__global__ void v_transpose(const ushort* __restrict__ qkv, ushort* __restrict__ Vt) {
    __shared__ ushort tile[32][33];
    int tx = threadIdx.x, ty = threadIdx.y; // 32 x 8
    int s0 = blockIdx.x * 32;
    int d0 = blockIdx.y * 32;
    int bh = blockIdx.z;
    int b = bh >> 4, h = bh & 15;
    for (int i = 0; i < 4; ++i) {
        int s = s0 + ty + i * 8;
        tile[ty + i * 8][tx] = qkv[((size_t)(b * SEQ + s)) * QKV_LD + 2 * D_MODEL + h * HD + d0 + tx];
    }
    __syncthreads();
    for (int i = 0; i < 4; ++i) {
        int d = d0 + ty + i * 8;
        Vt[((size_t)bh * HD + d) * SEQ + s0 + tx] = tile[tx][ty + i * 8];
    }
}

// ---------------- MFMA flash attention ----------------
__global__ __launch_bounds__(256) void attn_mfma(const ushort* __restrict__ Qb,
                                                 const ushort* __restrict__ Kb,
                                                 const ushort* __restrict__ Vt,
                                                 ushort* __restrict__ ctx) {
    __shared__ ushort smem[25600]; // Ks[0,8192) Vts[8192,16384) Ps[16384,25600)
    ushort* Ks = smem;          // [64][128], 16B chunks swizzled: c' = c ^ (row&15)
    ushort* Vts = smem + 8192;  // [128][64], 16B chunks swizzled: c' = c ^ (row&7)
    ushort* Ps = smem + 16384;  // [128][72] (pad 8 => 144B rows, 16B aligned)

    int t = threadIdx.x;
    int w = t >> 6, l = t & 63;
    int l31 = l & 31, g = l >> 5;
    int q0 = blockIdx.x * 128;
    int bh = blockIdx.y;
    int b = bh >> 4, h = bh & 15;

    int qrow = q0 + w * 32 + l31;
    const ushort* Qg = Qb + ((size_t)bh * SEQ + qrow) * HD;
    short8 qf[8];
#pragma unroll
    for (int kc = 0; kc < 8; kc++)
        qf[kc] = *(const short8*)(Qg + kc * 16 + g * 8);

    f32x16 O[4];
#pragma unroll
    for (int di = 0; di < 4; di++) O[di] = (f32x16)0.0f;
    float m_run = -INFINITY, l_run = 0.0f;

    const ushort* KgB = Kb + (size_t)bh * SEQ * HD;
    const ushort* VtB = Vt + (size_t)bh * HD * SEQ;

    for (int k0 = 0; k0 < SEQ; k0 += 64) {
        __syncthreads();
#pragma unroll
        for (int c2 = 0; c2 < 4; c2++) {
            int f = c2 * 256 + t;
            int r = f >> 4, c = f & 15;
            int cp = c ^ (r & 15);
            uint4 v = *(const uint4*)(KgB + (size_t)(k0 + r) * HD + c * 8);
            *(uint4*)(Ks + r * 128 + cp * 8) = v;
        }
#pragma unroll
        for (int c2 = 0; c2 < 4; c2++) {
            int f = c2 * 256 + t;
            int d = f >> 3, c = f & 7;
            int cp = c ^ (d & 7);
            uint4 v = *(const uint4*)(VtB + (size_t)d * SEQ + k0 + c * 8);
            *(uint4*)(Vts + d * 64 + cp * 8) = v;
        }
        __syncthreads();

        f32x16 St[2];
        St[0] = (f32x16)0.0f;
        St[1] = (f32x16)0.0f;
#pragma unroll
        for (int ki = 0; ki < 2; ki++) {
            int row = ki * 32 + l31;
#pragma unroll
            for (int kc = 0; kc < 8; kc++) {
                int cp = (kc * 2 + g) ^ (row & 15);
                short8 a = *(const short8*)(Ks + row * 128 + cp * 8);
                St[ki] = __builtin_amdgcn_mfma_f32_32x32x16_bf16(a, qf[kc], St[ki], 0, 0, 0);
            }
        }

        float mx = -INFINITY;
#pragma unroll
        for (int ki = 0; ki < 2; ki++)
#pragma unroll
            for (int r = 0; r < 16; r++) mx = fmaxf(mx, St[ki][r]);
        mx = fmaxf(mx, __shfl_xor(mx, 32));
        float mn = fmaxf(m_run, mx);
        float alpha = __expf(m_run - mn);
        m_run = mn;
        float psum = 0.0f;
#pragma unroll
        for (int ki = 0; ki < 2; ki++)
#pragma unroll
            for (int r = 0; r < 16; r++) {
                float p = __expf(St[ki][r] - mn);
                St[ki][r] = p;
                psum += p;
            }
        psum += __shfl_xor(psum, 32);
        l_run = l_run * alpha + psum;
#pragma unroll
        for (int di = 0; di < 4; di++)
#pragma unroll
            for (int r = 0; r < 16; r++) O[di][r] *= alpha;

        {
            int qloc = w * 32 + l31;
            ushort* Pr = Ps + qloc * 72;
#pragma unroll
            for (int ki = 0; ki < 2; ki++)
#pragma unroll
                for (int u = 0; u < 4; u++) {
                    ushort4 pk;
                    pk.x = f2bf(St[ki][4 * u + 0]);
                    pk.y = f2bf(St[ki][4 * u + 1]);
                    pk.z = f2bf(St[ki][4 * u + 2]);
                    pk.w = f2bf(St[ki][4 * u + 3]);
                    *(ushort4*)(Pr + ki * 32 + 8 * u + 4 * g) = pk;
                }
        }

        {
            int qloc = w * 32 + l31;
            short8 pb[4];
#pragma unroll
            for (int kc = 0; kc < 4; kc++)
                pb[kc] = *(const short8*)(Ps + qloc * 72 + kc * 16 + g * 8);
#pragma unroll
            for (int di = 0; di < 4; di++) {
                int d = di * 32 + l31;
#pragma unroll
                for (int kc = 0; kc < 4; kc++) {
                    int cp = (kc * 2 + g) ^ (d & 7);
                    short8 va = *(const short8*)(Vts + d * 64 + cp * 8);
                    O[di] = __builtin_amdgcn_mfma_f32_32x32x16_bf16(va, pb[kc], O[di], 0, 0, 0);
                }
            }
        }
    }

    __syncthreads();
    float inv = 1.0f / l_run;
    ushort* ob = smem; // [128][128] rows = block-local q
    {
        int qloc = w * 32 + l31;
        ushort* orow = ob + qloc * 128;
#pragma unroll
        for (int di = 0; di < 4; di++)
#pragma unroll
            for (int u = 0; u < 4; u++) {
                ushort4 pk;
                pk.x = f2bf(O[di][4 * u + 0] * inv);
                pk.y = f2bf(O[di][4 * u + 1] * inv);
                pk.z = f2bf(O[di][4 * u + 2] * inv);
                pk.w = f2bf(O[di][4 * u + 3] * inv);
                *(ushort4*)(orow + di * 32 + 8 * u + 4 * g) = pk;
            }
    }
#pragma unroll
    for (int p = 0; p < 8; p++) {
        int qloc = w * 32 + p * 4 + (l >> 4);
        int c16 = l & 15;
        uint4 v = *(const uint4*)(ob + qloc * 128 + c16 * 8);
        size_t tok = (size_t)b * SEQ + q0 + qloc;
        *(uint4*)(ctx + tok * D_MODEL + h * HD + c16 * 8) = v;
    }
}

extern "C" void kernel_launch(void* const* d_in, const int* in_sizes, int n_in,
                              void* d_out, int out_size, void* d_ws, size_t ws_size,
                              hipStream_t stream) {
    const float* x    = (const float*)d_in[0];
    const float* Wqkv = (const float*)d_in[1];
    const float* bqkv = (const float*)d_in[2];
    const float* Wo   = (const float*)d_in[3];
    const float* bo   = (const float*)d_in[4];
    float* out = (float*)d_out;

    char* ws = (char*)d_ws;
    ushort* x_bf   = (ushort*)(ws);                  // 16 MB [0,16M)
    ushort* wqkvT  = (ushort*)(ws + 16777216);       // 24 MB
    ushort* woT    = (ushort*)(ws + 41943040);       //  8 MB
    ushort* qkv_bf = (ushort*)(ws + 50331648);       // 48 MB: [4096][6144] bf16
    ushort* Qb     = (ushort*)(ws + 100663296);      // 16 MB: [32][2048][128] bf16
    ushort* Kb     = (ushort*)(ws + 117440512);      // 16 MB
    ushort* VtG    = (ushort*)(ws + 134217728);      // 16 MB: [32][128][2048] bf16
    ushort* ctx    = (ushort*)(ws + 150994944);      // 16 MB -> total 160 MB
    // rope table overlaps ctx region (1 MB): consumed by rope_cast_qk BEFORE attn writes ctx.
    float2* rtab   = (float2*)(ws + 150994944);

    rope_table<<<512, 256, 0, stream>>>(rtab);
    cvt_bf16_kernel<<<8192, 256, 0, stream>>>(x, x_bf, 2097152);
    transpose_bf16_kernel<<<dim3(192, 64), dim3(32, 8), 0, stream>>>(Wqkv, wqkvT, 2048, 6144);
    transpose_bf16_kernel<<<dim3(64, 64), dim3(32, 8), 0, stream>>>(Wo, woT, 2048, 2048);
    // qkv = x @ Wqkv + bqkv  -> bf16 (256x256 pipelined)
    gemm256<ushort, 2><<<dim3(24, 16), 512, 0, stream>>>(x_bf, wqkvT, bqkv, qkv_bf, 4096, 6144, 2048);
    // RoPE + reshape q,k ; transpose v
    rope_cast_qk<<<32768, 256, 0, stream>>>(qkv_bf, rtab, Qb, Kb);
    v_transpose<<<dim3(64, 4, 32), dim3(32, 8), 0, stream>>>(qkv_bf, VtG);
    // MFMA flash attention -> ctx bf16
    attn_mfma<<<dim3(16, 32), 256, 0, stream>>>(Qb, Kb, VtG, ctx);
    // out = ctx @ Wo + bo (256x128 pipelined, 256 blocks = full machine)
    gemm256<float, 1><<<dim3(16, 16), 512, 0, stream>>>(ctx, woT, bo, out, 4096, 2048, 2048);
}

// Round 5
// 423.368 us; speedup vs baseline: 1.1253x; 1.0171x over previous
//
#include <hip/hip_runtime.h>
#include <hip/hip_bf16.h>
#include <cstdint>
#include <type_traits>

#define D_MODEL 2048
#define NH 16
#define HD 128
#define SEQ 2048
#define QKV_LD (3 * D_MODEL) // 6144

typedef __attribute__((ext_vector_type(8))) short short8;
typedef __attribute__((ext_vector_type(4))) float f32x4;
typedef __attribute__((ext_vector_type(16))) float f32x16;

__device__ __forceinline__ ushort f2bf(float f) {
    union { float f; uint32_t u; } c; c.f = f;
    uint32_t u = c.u;
    uint32_t r = (u + 0x7FFFu + ((u >> 16) & 1u)) >> 16;
    return (ushort)r;
}
__device__ __forceinline__ float bf2f(ushort b) {
    union { uint32_t u; float f; } c; c.u = ((uint32_t)b) << 16;
    return c.f;
}

// async global->LDS, 16B per lane. LDS dest = wave-uniform base + lane*16 (HW).
__device__ __forceinline__ void load_lds16(const ushort* g, ushort* l) {
    __builtin_amdgcn_global_load_lds(
        (const __attribute__((address_space(1))) void*)g,
        (__attribute__((address_space(3))) void*)l, 16, 0, 0);
}

#define WAITV(N) asm volatile("s_waitcnt vmcnt(" #N ")" ::: "memory")
#define BARF()   do { __builtin_amdgcn_s_barrier(); \
                      asm volatile("" ::: "memory"); } while (0)
#define PRIO1    __builtin_amdgcn_s_setprio(1)
#define PRIO0    __builtin_amdgcn_s_setprio(0)

// ---------------- fp32 -> bf16 cast (x) ----------------
__global__ void cvt_bf16_kernel(const float* __restrict__ in, ushort* __restrict__ out, int n4) {
    int idx = blockIdx.x * blockDim.x + threadIdx.x;
    if (idx >= n4) return;
    float4 v = ((const float4*)in)[idx];
    ushort4 o;
    o.x = f2bf(v.x); o.y = f2bf(v.y); o.z = f2bf(v.z); o.w = f2bf(v.w);
    ((ushort4*)out)[idx] = o;
}

// ---------------- fp32 [R][C] -> bf16 [C][R] transpose ----------------
__global__ void transpose_bf16_kernel(const float* __restrict__ in, ushort* __restrict__ out,
                                      int R, int C) {
    __shared__ float tile[32][33];
    int tx = threadIdx.x, ty = threadIdx.y; // 32 x 8
    int c0 = blockIdx.x * 32, r0 = blockIdx.y * 32;
    for (int i = 0; i < 4; ++i) {
        int r = r0 + ty + i * 8;
        tile[ty + i * 8][tx] = in[(size_t)r * C + c0 + tx];
    }
    __syncthreads();
    for (int i = 0; i < 4; ++i) {
        int c = c0 + ty + i * 8;
        out[(size_t)c * R + r0 + tx] = f2bf(tile[tx][ty + i * 8]);
    }
}

// ================= 256 x (128*NHALF) pipelined bf16 GEMM (used for out-proj) ==========
#define B_ROWOFF(L) (NHALF == 2 ? (((L) & 1) * 128 + ((L) >> 1) * 32) : ((L) * 64))
#define STAGE_A(L, T_, B_) load_lds16(Ag + (size_t)(L) * 64 * K + (size_t)(T_) * 64, \
                                      smA + (B_) * 16384 + (L) * 4096 + ldsW)
#define STAGE_B(L, T_, B_) load_lds16(Bg + (size_t)B_ROWOFF(L) * K + (size_t)(T_) * 64, \
                                      smB + (B_) * (8192 * NHALF) + (L) * 4096 + ldsW)
#define READ_A(MH) do { const ushort* _ab = smA + cb * 16384 + aRow + (MH) * 4096; \
    _Pragma("unroll") for (int i_ = 0; i_ < 4; ++i_) { \
        af[i_][0] = *(const short8*)(_ab + i_ * 1024 + pc0); \
        af[i_][1] = *(const short8*)(_ab + i_ * 1024 + pc1); } } while (0)
#define READ_BH(dst, NHh) do { const ushort* _bb = smB + cb * (8192 * NHALF) + (NHh) * 8192 + bRow; \
    _Pragma("unroll") for (int j_ = 0; j_ < 2; ++j_) { \
        dst[j_][0] = *(const short8*)(_bb + j_ * 1024 + pc0); \
        dst[j_][1] = *(const short8*)(_bb + j_ * 1024 + pc1); } } while (0)
#define MFMA_PH(MH, NHh, bf) do { \
    _Pragma("unroll") for (int i_ = 0; i_ < 4; ++i_) \
    _Pragma("unroll") for (int j_ = 0; j_ < 2; ++j_) { \
        acc[(MH) * 4 + i_][(NHh) * 2 + j_] = __builtin_amdgcn_mfma_f32_16x16x32_bf16( \
            af[i_][0], bf[j_][0], acc[(MH) * 4 + i_][(NHh) * 2 + j_], 0, 0, 0); \
        acc[(MH) * 4 + i_][(NHh) * 2 + j_] = __builtin_amdgcn_mfma_f32_16x16x32_bf16( \
            af[i_][1], bf[j_][1], acc[(MH) * 4 + i_][(NHh) * 2 + j_], 0, 0, 0); } } while (0)

template <typename OutT, int NHALF>
__global__ __launch_bounds__(512, 2) void gemm256(
    const ushort* __restrict__ A,   // [M][K] bf16
    const ushort* __restrict__ Bt,  // [N][K] bf16
    const float* __restrict__ bias, // [N]
    OutT* __restrict__ C,           // [M][N]
    int M, int N, int K)
{
    __shared__ __align__(16) ushort sm[32768 + 2 * 8192 * NHALF];
    ushort* smA = sm;
    ushort* smB = sm + 32768;

    int t = threadIdx.x;
    int w = t >> 6, lane = t & 63;
    int lr = lane & 15, lh = lane >> 4;
    int wm_idx = w >> 2, wn_idx = w & 3;
    int m0 = blockIdx.y * 256, n0 = blockIdx.x * (128 * NHALF);

    int srow = t >> 3;
    int scol = ((t & 7) ^ (srow & 7)) << 3;
    const ushort* Ag = A + (size_t)(m0 + srow) * K + scol;
    int bq = (NHALF == 2) ? ((srow >> 5) * 64 + (srow & 31)) : srow;
    const ushort* Bg = Bt + (size_t)(n0 + bq) * K + scol;
    int ldsW = w * 512;

    int pc0 = (lh ^ (lr & 7)) << 3;
    int pc1 = ((4 + lh) ^ (lr & 7)) << 3;
    int aRow = (wm_idx * 128 + lr) * 64;
    int bRow = (wn_idx * 32 + lr) * 64;

    f32x4 acc[8][2 * NHALF];
#pragma unroll
    for (int i = 0; i < 8; ++i)
#pragma unroll
        for (int j = 0; j < 2 * NHALF; ++j) acc[i][j] = (f32x4)0.0f;
    short8 af[4][2], bf0[2][2], bf1[2][2];

    int NT = K >> 6;

    if constexpr (NHALF == 2) {
        STAGE_A(0, 0, 0); STAGE_A(2, 0, 0); STAGE_B(0, 0, 0); STAGE_B(1, 0, 0);
        STAGE_B(2, 0, 0); STAGE_B(3, 0, 0);
        STAGE_A(1, 0, 0); STAGE_A(3, 0, 0);
        WAITV(4);
    } else {
        STAGE_A(0, 0, 0); STAGE_A(2, 0, 0); STAGE_B(0, 0, 0);
        STAGE_B(1, 0, 0); STAGE_A(1, 0, 0); STAGE_A(3, 0, 0);
        WAITV(2);
    }
    BARF();

    for (int T = 0; T < NT; ++T) {
        int cb = T & 1, nb = cb ^ 1;
        bool pf = (T + 1 < NT);
        if constexpr (NHALF == 2) {
            READ_A(0); READ_BH(bf0, 0);
            if (pf) { STAGE_A(0, T + 1, nb); STAGE_A(2, T + 1, nb);
                      STAGE_B(0, T + 1, nb); STAGE_B(1, T + 1, nb); }
            BARF();
            PRIO1; MFMA_PH(0, 0, bf0); PRIO0;
            if (pf) WAITV(6); else WAITV(2);
            BARF();
            READ_BH(bf1, 1);
            if (pf) { STAGE_B(2, T + 1, nb); STAGE_B(3, T + 1, nb); }
            BARF();
            PRIO1; MFMA_PH(0, 1, bf1); PRIO0;
            if (pf) WAITV(6); else WAITV(0);
            BARF();
            READ_A(1);
            if (pf) { STAGE_A(1, T + 1, nb); STAGE_A(3, T + 1, nb); }
            BARF();
            PRIO1; MFMA_PH(1, 1, bf1); MFMA_PH(1, 0, bf0); PRIO0;
            if (pf) WAITV(4);
            BARF();
        } else {
            READ_A(0); READ_BH(bf0, 0);
            if (pf) { STAGE_A(0, T + 1, nb); STAGE_A(2, T + 1, nb); STAGE_B(0, T + 1, nb); }
            BARF();
            PRIO1; MFMA_PH(0, 0, bf0); PRIO0;
            if (pf) WAITV(3); else WAITV(0);
            BARF();
            READ_A(1);
            if (pf) { STAGE_B(1, T + 1, nb); STAGE_A(1, T + 1, nb); STAGE_A(3, T + 1, nb); }
            BARF();
            PRIO1; MFMA_PH(1, 0, bf0); PRIO0;
            if (pf) WAITV(2);
            BARF();
        }
    }

    float bv[2 * NHALF];
#pragma unroll
    for (int jj = 0; jj < 2 * NHALF; ++jj) bv[jj] = bias[n0 + wn_idx * 32 * NHALF + jj * 16 + lr];
#pragma unroll
    for (int ii = 0; ii < 8; ++ii) {
        int row = m0 + wm_idx * 128 + ii * 16 + lh * 4;
#pragma unroll
        for (int jj = 0; jj < 2 * NHALF; ++jj) {
            int col = n0 + wn_idx * 32 * NHALF + jj * 16 + lr;
#pragma unroll
            for (int r = 0; r < 4; ++r) {
                float v = acc[ii][jj][r] + bv[jj];
                if constexpr (std::is_same<OutT, ushort>::value)
                    C[(size_t)(row + r) * N + col] = f2bf(v);
                else
                    C[(size_t)(row + r) * N + col] = v;
            }
        }
    }
}

// ================= 128 x 384 pipelined bf16 GEMM (QKV projection) =================
// BM=128, BN=384, BK=64; 8 waves (2M x 4N), per-wave 64x96 (4x6 frags).
// Grid (N/384, M/128) = (16, 32) = 512 blocks = exactly 2 full dispatch rounds.
// LDS 128 KiB: A dbuf 2x[128][64] (2x16KB), B dbuf 2x[384][64] h-major (2x48KB).
// B LDS p-row = h*128 + wn*32 + j'*16 + lr holds global row wn*96 + h*32 + j'*16 + lr.
// 16B chunk c of p-row r at phys c^(r&7); linear gload_lds dest + pre-swizzled source.
// 3 phases/K-tile: {READ A+B(h0) | MFMA h0} {READ B(h1) | MFMA h1} {READ B(h2) | MFMA h2},
// issue for T+1: P1:{A0,A1,B0} P2:{B1,B2,B3} P3:{B4,B5}.
// Counted vmcnt (FIFO-verified): steady ends = 5/6/4; tail = 2/0/-; prologue 8 issues, wait 4.
#define STAGE_A3(L, T_, B_) load_lds16(Ag + (size_t)(L) * 64 * K + (size_t)(T_) * 64, \
                                       smA + (B_) * 8192 + (L) * 4096 + ldsW)
#define STAGE_B3(L, T_, B_) load_lds16(Bg + (size_t)((((L) & 1) * 2 + wnp) * 96 + ((L) >> 1) * 32 + rb) * K + (size_t)(T_) * 64, \
                                       smB + (B_) * 24576 + (L) * 4096 + ldsW)
#define READ_A3() do { const ushort* _ab = smA + cb * 8192 + aRow; \
    _Pragma("unroll") for (int i_ = 0; i_ < 4; ++i_) { \
        af[i_][0] = *(const short8*)(_ab + i_ * 1024 + pc0); \
        af[i_][1] = *(const short8*)(_ab + i_ * 1024 + pc1); } } while (0)
#define READ_B3(H) do { const ushort* _bb = smB + cb * 24576 + (H) * 8192 + bRow; \
    _Pragma("unroll") for (int j_ = 0; j_ < 2; ++j_) { \
        bfr[j_][0] = *(const short8*)(_bb + j_ * 1024 + pc0); \
        bfr[j_][1] = *(const short8*)(_bb + j_ * 1024 + pc1); } } while (0)
#define MFMA_P3(H) do { \
    _Pragma("unroll") for (int i_ = 0; i_ < 4; ++i_) \
    _Pragma("unroll") for (int j_ = 0; j_ < 2; ++j_) { \
        acc[i_][(H) * 2 + j_] = __builtin_amdgcn_mfma_f32_16x16x32_bf16( \
            af[i_][0], bfr[j_][0], acc[i_][(H) * 2 + j_], 0, 0, 0); \
        acc[i_][(H) * 2 + j_] = __builtin_amdgcn_mfma_f32_16x16x32_bf16( \
            af[i_][1], bfr[j_][1], acc[i_][(H) * 2 + j_], 0, 0, 0); } } while (0)

__global__ __launch_bounds__(512, 2) void gemm384(
    const ushort* __restrict__ A,   // [M][K] bf16
    const ushort* __restrict__ Bt,  // [N][K] bf16
    const float* __restrict__ bias, // [N]
    ushort* __restrict__ C,         // [M][N] bf16
    int M, int N, int K)
{
    __shared__ __align__(16) ushort sm[65536]; // A [0,16384), B [16384,65536)
    ushort* smA = sm;
    ushort* smB = sm + 16384;

    int t = threadIdx.x;
    int w = t >> 6, lane = t & 63;
    int lr = lane & 15, lh = lane >> 4;
    int wm_idx = w >> 2, wn_idx = w & 3;    // 2 x 4 wave grid, per-wave 64 x 96
    int m0 = blockIdx.y * 128, n0 = blockIdx.x * 384;

    int srow = t >> 3;                       // 0..63
    int scol = ((t & 7) ^ (srow & 7)) << 3;  // pre-swizzled source chunk
    const ushort* Ag = A + (size_t)(m0 + srow) * K + scol;
    const ushort* Bg = Bt + (size_t)n0 * K + scol;
    int wnp = srow >> 5;                     // B perm helpers
    int rb = srow & 31;
    int ldsW = w * 512;

    int pc0 = (lh ^ (lr & 7)) << 3;
    int pc1 = ((4 + lh) ^ (lr & 7)) << 3;
    int aRow = (wm_idx * 64 + lr) * 64;
    int bRow = (wn_idx * 32 + lr) * 64;

    f32x4 acc[4][6];
#pragma unroll
    for (int i = 0; i < 4; ++i)
#pragma unroll
        for (int j = 0; j < 6; ++j) acc[i][j] = (f32x4)0.0f;
    short8 af[4][2], bfr[2][2];

    int NT = K >> 6;

    // prologue: tile 0, FIFO [A0,A1,B0,B1,B2,B3,B4,B5]; need first 4 for P1
    STAGE_A3(0, 0, 0); STAGE_A3(1, 0, 0); STAGE_B3(0, 0, 0); STAGE_B3(1, 0, 0);
    STAGE_B3(2, 0, 0); STAGE_B3(3, 0, 0); STAGE_B3(4, 0, 0); STAGE_B3(5, 0, 0);
    WAITV(4);
    BARF();

    for (int T = 0; T < NT; ++T) {
        int cb = T & 1, nb = cb ^ 1;
        bool pf = (T + 1 < NT);
        // ---- P1: A x B-half0 ----
        READ_A3(); READ_B3(0);
        if (pf) { STAGE_A3(0, T + 1, nb); STAGE_A3(1, T + 1, nb); STAGE_B3(0, T + 1, nb); }
        BARF();
        PRIO1; MFMA_P3(0); PRIO0;
        if (pf) WAITV(5); else WAITV(2);
        BARF();
        // ---- P2: A x B-half1 (A cached) ----
        READ_B3(1);
        if (pf) { STAGE_B3(1, T + 1, nb); STAGE_B3(2, T + 1, nb); STAGE_B3(3, T + 1, nb); }
        BARF();
        PRIO1; MFMA_P3(1); PRIO0;
        if (pf) WAITV(6); else WAITV(0);
        BARF();
        // ---- P3: A x B-half2 ----
        READ_B3(2);
        if (pf) { STAGE_B3(4, T + 1, nb); STAGE_B3(5, T + 1, nb); }
        BARF();
        PRIO1; MFMA_P3(2); PRIO0;
        if (pf) WAITV(4);
        BARF();
    }

    float bv[6];
#pragma unroll
    for (int jj = 0; jj < 6; ++jj) bv[jj] = bias[n0 + wn_idx * 96 + jj * 16 + lr];
#pragma unroll
    for (int ii = 0; ii < 4; ++ii) {
        int row = m0 + wm_idx * 64 + ii * 16 + lh * 4;
#pragma unroll
        for (int jj = 0; jj < 6; ++jj) {
            int col = n0 + wn_idx * 96 + jj * 16 + lr;
#pragma unroll
            for (int r = 0; r < 4; ++r) {
                float v = acc[ii][jj][r] + bv[jj];
                C[(size_t)(row + r) * N + col] = f2bf(v);
            }
        }
    }
}

// ---------------- RoPE cos/sin table: [s][j] -> (cos, sin), 2048*64 entries ----------------
__global__ void rope_table(float2* __restrict__ tab) {
    int i = blockIdx.x * blockDim.x + threadIdx.x; // 0..131071
    int s = i >> 6, j = i & 63;
    float theta = powf(10000.0f, -(float)j * (1.0f / 64.0f));
    float ang = (float)s * theta;
    float sn, cs;
    sincosf(ang, &sn, &cs);
    tab[i] = make_float2(cs, sn);
}

// ---------------- RoPE + cast + reshape: qkv_bf16 -> Qb,Kb [bh][s][128] ----------------
__global__ void rope_cast_qk(const ushort* __restrict__ qkv,
                             const float2* __restrict__ tab,
                             ushort* __restrict__ Qb, ushort* __restrict__ Kb) {
    int t = threadIdx.x;
    int wv = blockIdx.x * 4 + (t >> 6); // 0..131071
    int j = t & 63;
    int bs = wv >> 5;
    int rem = wv & 31;
    int which = rem >> 4;  // 0=q, 1=k
    int h = rem & 15;
    int s = bs & 2047;
    int b = bs >> 11;
    size_t src = (size_t)bs * QKV_LD + which * D_MODEL + h * HD;
    uint32_t pr = *(const uint32_t*)(qkv + src + 2 * j);
    float x1 = bf2f((ushort)(pr & 0xffff));
    float x2 = bf2f((ushort)(pr >> 16));
    float2 cspair = tab[(s << 6) + j];
    float cs = cspair.x, sn = cspair.y;
    float sc = which ? 1.0f : 0.08838834764831845f; // fold 1/sqrt(128) into Q
    float o1 = (x1 * cs - x2 * sn) * sc;
    float o2 = (x1 * sn + x2 * cs) * sc;
    ushort* dst = which ? Kb : Qb;
    size_t obase = ((size_t)(b * NH + h) * SEQ + s) * HD;
    dst[obase + j] = f2bf(o1);
    dst[obase + 64 + j] = f2bf(o2);
}

// ---------------- V transpose: qkv_bf16 v-part -> Vt [bh][d=128][s=2048] ----------------
__global__ void v_transpose(const ushort* __restrict__ qkv, ushort* __restrict__ Vt) {
    __shared__ ushort tile[32][33];
    int tx = threadIdx.x, ty = threadIdx.y; // 32 x 8
    int s0 = blockIdx.x * 32;
    int d0 = blockIdx.y * 32;
    int bh = blockIdx.z;
    int b = bh >> 4, h = bh & 15;
    for (int i = 0; i < 4; ++i) {
        int s = s0 + ty + i * 8;
        tile[ty + i * 8][tx] = qkv[((size_t)(b * SEQ + s)) * QKV_LD + 2 * D_MODEL + h * HD + d0 + tx];
    }
    __syncthreads();
    for (int i = 0; i < 4; ++i) {
        int d = d0 + ty + i * 8;
        Vt[((size_t)bh * HD + d) * SEQ + s0 + tx] = tile[tx][ty + i * 8];
    }
}

// ---------------- MFMA flash attention ----------------
__global__ __launch_bounds__(256) void attn_mfma(const ushort* __restrict__ Qb,
                                                 const ushort* __restrict__ Kb,
                                                 const ushort* __restrict__ Vt,
                                                 ushort* __restrict__ ctx) {
    __shared__ ushort smem[25600]; // Ks[0,8192) Vts[8192,16384) Ps[16384,25600)
    ushort* Ks = smem;          // [64][128], 16B chunks swizzled: c' = c ^ (row&15)
    ushort* Vts = smem + 8192;  // [128][64], 16B chunks swizzled: c' = c ^ (row&7)
    ushort* Ps = smem + 16384;  // [128][72] (pad 8 => 144B rows, 16B aligned)

    int t = threadIdx.x;
    int w = t >> 6, l = t & 63;
    int l31 = l & 31, g = l >> 5;
    int q0 = blockIdx.x * 128;
    int bh = blockIdx.y;
    int b = bh >> 4, h = bh & 15;

    int qrow = q0 + w * 32 + l31;
    const ushort* Qg = Qb + ((size_t)bh * SEQ + qrow) * HD;
    short8 qf[8];
#pragma unroll
    for (int kc = 0; kc < 8; kc++)
        qf[kc] = *(const short8*)(Qg + kc * 16 + g * 8);

    f32x16 O[4];
#pragma unroll
    for (int di = 0; di < 4; di++) O[di] = (f32x16)0.0f;
    float m_run = -INFINITY, l_run = 0.0f;

    const ushort* KgB = Kb + (size_t)bh * SEQ * HD;
    const ushort* VtB = Vt + (size_t)bh * HD * SEQ;

    for (int k0 = 0; k0 < SEQ; k0 += 64) {
        __syncthreads();
#pragma unroll
        for (int c2 = 0; c2 < 4; c2++) {
            int f = c2 * 256 + t;
            int r = f >> 4, c = f & 15;
            int cp = c ^ (r & 15);
            uint4 v = *(const uint4*)(KgB + (size_t)(k0 + r) * HD + c * 8);
            *(uint4*)(Ks + r * 128 + cp * 8) = v;
        }
#pragma unroll
        for (int c2 = 0; c2 < 4; c2++) {
            int f = c2 * 256 + t;
            int d = f >> 3, c = f & 7;
            int cp = c ^ (d & 7);
            uint4 v = *(const uint4*)(VtB + (size_t)d * SEQ + k0 + c * 8);
            *(uint4*)(Vts + d * 64 + cp * 8) = v;
        }
        __syncthreads();

        f32x16 St[2];
        St[0] = (f32x16)0.0f;
        St[1] = (f32x16)0.0f;
        PRIO1;
#pragma unroll
        for (int ki = 0; ki < 2; ki++) {
            int row = ki * 32 + l31;
#pragma unroll
            for (int kc = 0; kc < 8; kc++) {
                int cp = (kc * 2 + g) ^ (row & 15);
                short8 a = *(const short8*)(Ks + row * 128 + cp * 8);
                St[ki] = __builtin_amdgcn_mfma_f32_32x32x16_bf16(a, qf[kc], St[ki], 0, 0, 0);
            }
        }
        PRIO0;

        float mx = -INFINITY;
#pragma unroll
        for (int ki = 0; ki < 2; ki++)
#pragma unroll
            for (int r = 0; r < 16; r++) mx = fmaxf(mx, St[ki][r]);
        mx = fmaxf(mx, __shfl_xor(mx, 32));
        float mn = fmaxf(m_run, mx);
        float alpha = __expf(m_run - mn);
        m_run = mn;
        float psum = 0.0f;
#pragma unroll
        for (int ki = 0; ki < 2; ki++)
#pragma unroll
            for (int r = 0; r < 16; r++) {
                float p = __expf(St[ki][r] - mn);
                St[ki][r] = p;
                psum += p;
            }
        psum += __shfl_xor(psum, 32);
        l_run = l_run * alpha + psum;
#pragma unroll
        for (int di = 0; di < 4; di++)
#pragma unroll
            for (int r = 0; r < 16; r++) O[di][r] *= alpha;

        {
            int qloc = w * 32 + l31;
            ushort* Pr = Ps + qloc * 72;
#pragma unroll
            for (int ki = 0; ki < 2; ki++)
#pragma unroll
                for (int u = 0; u < 4; u++) {
                    ushort4 pk;
                    pk.x = f2bf(St[ki][4 * u + 0]);
                    pk.y = f2bf(St[ki][4 * u + 1]);
                    pk.z = f2bf(St[ki][4 * u + 2]);
                    pk.w = f2bf(St[ki][4 * u + 3]);
                    *(ushort4*)(Pr + ki * 32 + 8 * u + 4 * g) = pk;
                }
        }

        {
            int qloc = w * 32 + l31;
            short8 pb[4];
#pragma unroll
            for (int kc = 0; kc < 4; kc++)
                pb[kc] = *(const short8*)(Ps + qloc * 72 + kc * 16 + g * 8);
            PRIO1;
#pragma unroll
            for (int di = 0; di < 4; di++) {
                int d = di * 32 + l31;
#pragma unroll
                for (int kc = 0; kc < 4; kc++) {
                    int cp = (kc * 2 + g) ^ (d & 7);
                    short8 va = *(const short8*)(Vts + d * 64 + cp * 8);
                    O[di] = __builtin_amdgcn_mfma_f32_32x32x16_bf16(va, pb[kc], O[di], 0, 0, 0);
                }
            }
            PRIO0;
        }
    }

    __syncthreads();
    float inv = 1.0f / l_run;
    ushort* ob = smem; // [128][128] rows = block-local q
    {
        int qloc = w * 32 + l31;
        ushort* orow = ob + qloc * 128;
#pragma unroll
        for (int di = 0; di < 4; di++)
#pragma unroll
            for (int u = 0; u < 4; u++) {
                ushort4 pk;
                pk.x = f2bf(O[di][4 * u + 0] * inv);
                pk.y = f2bf(O[di][4 * u + 1] * inv);
                pk.z = f2bf(O[di][4 * u + 2] * inv);
                pk.w = f2bf(O[di][4 * u + 3] * inv);
                *(ushort4*)(orow + di * 32 + 8 * u + 4 * g) = pk;
            }
    }
#pragma unroll
    for (int p = 0; p < 8; p++) {
        int qloc = w * 32 + p * 4 + (l >> 4);
        int c16 = l & 15;
        uint4 v = *(const uint4*)(ob + qloc * 128 + c16 * 8);
        size_t tok = (size_t)b * SEQ + q0 + qloc;
        *(uint4*)(ctx + tok * D_MODEL + h * HD + c16 * 8) = v;
    }
}

extern "C" void kernel_launch(void* const* d_in, const int* in_sizes, int n_in,
                              void* d_out, int out_size, void* d_ws, size_t ws_size,
                              hipStream_t stream) {
    const float* x    = (const float*)d_in[0];
    const float* Wqkv = (const float*)d_in[1];
    const float* bqkv = (const float*)d_in[2];
    const float* Wo   = (const float*)d_in[3];
    const float* bo   = (const float*)d_in[4];
    float* out = (float*)d_out;

    char* ws = (char*)d_ws;
    ushort* x_bf   = (ushort*)(ws);                  // 16 MB [0,16M)
    ushort* wqkvT  = (ushort*)(ws + 16777216);       // 24 MB
    ushort* woT    = (ushort*)(ws + 41943040);       //  8 MB
    ushort* qkv_bf = (ushort*)(ws + 50331648);       // 48 MB: [4096][6144] bf16
    ushort* Qb     = (ushort*)(ws + 100663296);      // 16 MB: [32][2048][128] bf16
    ushort* Kb     = (ushort*)(ws + 117440512);      // 16 MB
    ushort* VtG    = (ushort*)(ws + 134217728);      // 16 MB: [32][128][2048] bf16
    ushort* ctx    = (ushort*)(ws + 150994944);      // 16 MB -> total 160 MB
    // rope table overlaps ctx region (1 MB): consumed by rope_cast_qk BEFORE attn writes ctx.
    float2* rtab   = (float2*)(ws + 150994944);

    rope_table<<<512, 256, 0, stream>>>(rtab);
    cvt_bf16_kernel<<<8192, 256, 0, stream>>>(x, x_bf, 2097152);
    transpose_bf16_kernel<<<dim3(192, 64), dim3(32, 8), 0, stream>>>(Wqkv, wqkvT, 2048, 6144);
    transpose_bf16_kernel<<<dim3(64, 64), dim3(32, 8), 0, stream>>>(Wo, woT, 2048, 2048);
    // qkv = x @ Wqkv + bqkv -> bf16 (128x384 tiles, 512 blocks = 2 exact full rounds)
    gemm384<<<dim3(16, 32), 512, 0, stream>>>(x_bf, wqkvT, bqkv, qkv_bf, 4096, 6144, 2048);
    // RoPE + reshape q,k ; transpose v
    rope_cast_qk<<<32768, 256, 0, stream>>>(qkv_bf, rtab, Qb, Kb);
    v_transpose<<<dim3(64, 4, 32), dim3(32, 8), 0, stream>>>(qkv_bf, VtG);
    // MFMA flash attention -> ctx bf16
    attn_mfma<<<dim3(16, 32), 256, 0, stream>>>(Qb, Kb, VtG, ctx);
    // out = ctx @ Wo + bo (256x128, 256 blocks = full machine)
    gemm256<float, 1><<<dim3(16, 16), 512, 0, stream>>>(ctx, woT, bo, out, 4096, 2048, 2048);
}

// Round 6
// 405.739 us; speedup vs baseline: 1.1742x; 1.0434x over previous
//
#include <hip/hip_runtime.h>
#include <hip/hip_bf16.h>
#include <cstdint>
#include <type_traits>

#define D_MODEL 2048
#define NH 16
#define HD 128
#define SEQ 2048
#define QKV_LD (3 * D_MODEL) // 6144

typedef __attribute__((ext_vector_type(8))) short short8;
typedef __attribute__((ext_vector_type(4))) float f32x4;
typedef __attribute__((ext_vector_type(16))) float f32x16;

__device__ __forceinline__ ushort f2bf(float f) {
    union { float f; uint32_t u; } c; c.f = f;
    uint32_t u = c.u;
    uint32_t r = (u + 0x7FFFu + ((u >> 16) & 1u)) >> 16;
    return (ushort)r;
}
__device__ __forceinline__ float bf2f(ushort b) {
    union { uint32_t u; float f; } c; c.u = ((uint32_t)b) << 16;
    return c.f;
}

// async global->LDS, 16B per lane. LDS dest = wave-uniform base + lane*16 (HW).
__device__ __forceinline__ void load_lds16(const ushort* g, ushort* l) {
    __builtin_amdgcn_global_load_lds(
        (const __attribute__((address_space(1))) void*)g,
        (__attribute__((address_space(3))) void*)l, 16, 0, 0);
}

#define WAITV(N) asm volatile("s_waitcnt vmcnt(" #N ")" ::: "memory")
#define BARF()   do { __builtin_amdgcn_s_barrier(); \
                      asm volatile("" ::: "memory"); } while (0)
#define PRIO1    __builtin_amdgcn_s_setprio(1)
#define PRIO0    __builtin_amdgcn_s_setprio(0)

// ================= fused prep: rope_table + x->bf16 + W transposes (1 launch) ==========
__device__ __forceinline__ void transpose_body(const float* __restrict__ in,
                                               ushort* __restrict__ out,
                                               int R, int C, int bx, int by, int t,
                                               float (*tile)[33]) {
    int tx = t & 31, ty = t >> 5; // 32 x 8
    int c0 = bx * 32, r0 = by * 32;
    for (int i = 0; i < 4; ++i) {
        int r = r0 + ty + i * 8;
        tile[ty + i * 8][tx] = in[(size_t)r * C + c0 + tx];
    }
    __syncthreads();
    for (int i = 0; i < 4; ++i) {
        int c = c0 + ty + i * 8;
        out[(size_t)c * R + r0 + tx] = f2bf(tile[tx][ty + i * 8]);
    }
}

__global__ void prep_fused(const float* __restrict__ x, ushort* __restrict__ x_bf,
                           const float* __restrict__ Wqkv, ushort* __restrict__ wqkvT,
                           const float* __restrict__ Wo, ushort* __restrict__ woT,
                           float2* __restrict__ rtab) {
    __shared__ float tile[32][33];
    int blk = blockIdx.x;
    int t = threadIdx.x;
    if (blk < 512) {
        // rope cos/sin table: [s][j], same math as original per-element path
        int i = blk * 256 + t; // 0..131071
        int s = i >> 6, j = i & 63;
        float theta = powf(10000.0f, -(float)j * (1.0f / 64.0f));
        float ang = (float)s * theta;
        float sn, cs;
        sincosf(ang, &sn, &cs);
        rtab[i] = make_float2(cs, sn);
    } else if (blk < 8704) {
        // x fp32 -> bf16, 8192 blocks x 256 x float4 = 2097152 exactly
        int idx = (blk - 512) * 256 + t;
        float4 v = ((const float4*)x)[idx];
        ushort4 o;
        o.x = f2bf(v.x); o.y = f2bf(v.y); o.z = f2bf(v.z); o.w = f2bf(v.w);
        ((ushort4*)x_bf)[idx] = o;
    } else if (blk < 20992) {
        // Wqkv [2048][6144] -> wqkvT bf16 [6144][2048]; grid was (192,64)
        int i = blk - 8704;
        transpose_body(Wqkv, wqkvT, 2048, 6144, i % 192, i / 192, t, tile);
    } else {
        // Wo [2048][2048] -> woT bf16; grid was (64,64)
        int i = blk - 20992;
        transpose_body(Wo, woT, 2048, 2048, i & 63, i >> 6, t, tile);
    }
}

// ================= 256 x (128*NHALF) pipelined bf16 GEMM (used for out-proj) ==========
#define B_ROWOFF(L) (NHALF == 2 ? (((L) & 1) * 128 + ((L) >> 1) * 32) : ((L) * 64))
#define STAGE_A(L, T_, B_) load_lds16(Ag + (size_t)(L) * 64 * K + (size_t)(T_) * 64, \
                                      smA + (B_) * 16384 + (L) * 4096 + ldsW)
#define STAGE_B(L, T_, B_) load_lds16(Bg + (size_t)B_ROWOFF(L) * K + (size_t)(T_) * 64, \
                                      smB + (B_) * (8192 * NHALF) + (L) * 4096 + ldsW)
#define READ_A(MH) do { const ushort* _ab = smA + cb * 16384 + aRow + (MH) * 4096; \
    _Pragma("unroll") for (int i_ = 0; i_ < 4; ++i_) { \
        af[i_][0] = *(const short8*)(_ab + i_ * 1024 + pc0); \
        af[i_][1] = *(const short8*)(_ab + i_ * 1024 + pc1); } } while (0)
#define READ_BH(dst, NHh) do { const ushort* _bb = smB + cb * (8192 * NHALF) + (NHh) * 8192 + bRow; \
    _Pragma("unroll") for (int j_ = 0; j_ < 2; ++j_) { \
        dst[j_][0] = *(const short8*)(_bb + j_ * 1024 + pc0); \
        dst[j_][1] = *(const short8*)(_bb + j_ * 1024 + pc1); } } while (0)
#define MFMA_PH(MH, NHh, bf) do { \
    _Pragma("unroll") for (int i_ = 0; i_ < 4; ++i_) \
    _Pragma("unroll") for (int j_ = 0; j_ < 2; ++j_) { \
        acc[(MH) * 4 + i_][(NHh) * 2 + j_] = __builtin_amdgcn_mfma_f32_16x16x32_bf16( \
            af[i_][0], bf[j_][0], acc[(MH) * 4 + i_][(NHh) * 2 + j_], 0, 0, 0); \
        acc[(MH) * 4 + i_][(NHh) * 2 + j_] = __builtin_amdgcn_mfma_f32_16x16x32_bf16( \
            af[i_][1], bf[j_][1], acc[(MH) * 4 + i_][(NHh) * 2 + j_], 0, 0, 0); } } while (0)

template <typename OutT, int NHALF>
__global__ __launch_bounds__(512, 2) void gemm256(
    const ushort* __restrict__ A,   // [M][K] bf16
    const ushort* __restrict__ Bt,  // [N][K] bf16
    const float* __restrict__ bias, // [N]
    OutT* __restrict__ C,           // [M][N]
    int M, int N, int K)
{
    __shared__ __align__(16) ushort sm[32768 + 2 * 8192 * NHALF];
    ushort* smA = sm;
    ushort* smB = sm + 32768;

    int t = threadIdx.x;
    int w = t >> 6, lane = t & 63;
    int lr = lane & 15, lh = lane >> 4;
    int wm_idx = w >> 2, wn_idx = w & 3;
    int m0 = blockIdx.y * 256, n0 = blockIdx.x * (128 * NHALF);

    int srow = t >> 3;
    int scol = ((t & 7) ^ (srow & 7)) << 3;
    const ushort* Ag = A + (size_t)(m0 + srow) * K + scol;
    int bq = (NHALF == 2) ? ((srow >> 5) * 64 + (srow & 31)) : srow;
    const ushort* Bg = Bt + (size_t)(n0 + bq) * K + scol;
    int ldsW = w * 512;

    int pc0 = (lh ^ (lr & 7)) << 3;
    int pc1 = ((4 + lh) ^ (lr & 7)) << 3;
    int aRow = (wm_idx * 128 + lr) * 64;
    int bRow = (wn_idx * 32 + lr) * 64;

    f32x4 acc[8][2 * NHALF];
#pragma unroll
    for (int i = 0; i < 8; ++i)
#pragma unroll
        for (int j = 0; j < 2 * NHALF; ++j) acc[i][j] = (f32x4)0.0f;
    short8 af[4][2], bf0[2][2], bf1[2][2];

    int NT = K >> 6;

    if constexpr (NHALF == 2) {
        STAGE_A(0, 0, 0); STAGE_A(2, 0, 0); STAGE_B(0, 0, 0); STAGE_B(1, 0, 0);
        STAGE_B(2, 0, 0); STAGE_B(3, 0, 0);
        STAGE_A(1, 0, 0); STAGE_A(3, 0, 0);
        WAITV(4);
    } else {
        STAGE_A(0, 0, 0); STAGE_A(2, 0, 0); STAGE_B(0, 0, 0);
        STAGE_B(1, 0, 0); STAGE_A(1, 0, 0); STAGE_A(3, 0, 0);
        WAITV(2);
    }
    BARF();

    for (int T = 0; T < NT; ++T) {
        int cb = T & 1, nb = cb ^ 1;
        bool pf = (T + 1 < NT);
        if constexpr (NHALF == 2) {
            READ_A(0); READ_BH(bf0, 0);
            if (pf) { STAGE_A(0, T + 1, nb); STAGE_A(2, T + 1, nb);
                      STAGE_B(0, T + 1, nb); STAGE_B(1, T + 1, nb); }
            BARF();
            PRIO1; MFMA_PH(0, 0, bf0); PRIO0;
            if (pf) WAITV(6); else WAITV(2);
            BARF();
            READ_BH(bf1, 1);
            if (pf) { STAGE_B(2, T + 1, nb); STAGE_B(3, T + 1, nb); }
            BARF();
            PRIO1; MFMA_PH(0, 1, bf1); PRIO0;
            if (pf) WAITV(6); else WAITV(0);
            BARF();
            READ_A(1);
            if (pf) { STAGE_A(1, T + 1, nb); STAGE_A(3, T + 1, nb); }
            BARF();
            PRIO1; MFMA_PH(1, 1, bf1); MFMA_PH(1, 0, bf0); PRIO0;
            if (pf) WAITV(4);
            BARF();
        } else {
            READ_A(0); READ_BH(bf0, 0);
            if (pf) { STAGE_A(0, T + 1, nb); STAGE_A(2, T + 1, nb); STAGE_B(0, T + 1, nb); }
            BARF();
            PRIO1; MFMA_PH(0, 0, bf0); PRIO0;
            if (pf) WAITV(3); else WAITV(0);
            BARF();
            READ_A(1);
            if (pf) { STAGE_B(1, T + 1, nb); STAGE_A(1, T + 1, nb); STAGE_A(3, T + 1, nb); }
            BARF();
            PRIO1; MFMA_PH(1, 0, bf0); PRIO0;
            if (pf) WAITV(2);
            BARF();
        }
    }

    float bv[2 * NHALF];
#pragma unroll
    for (int jj = 0; jj < 2 * NHALF; ++jj) bv[jj] = bias[n0 + wn_idx * 32 * NHALF + jj * 16 + lr];
#pragma unroll
    for (int ii = 0; ii < 8; ++ii) {
        int row = m0 + wm_idx * 128 + ii * 16 + lh * 4;
#pragma unroll
        for (int jj = 0; jj < 2 * NHALF; ++jj) {
            int col = n0 + wn_idx * 32 * NHALF + jj * 16 + lr;
#pragma unroll
            for (int r = 0; r < 4; ++r) {
                float v = acc[ii][jj][r] + bv[jj];
                if constexpr (std::is_same<OutT, ushort>::value)
                    C[(size_t)(row + r) * N + col] = f2bf(v);
                else
                    C[(size_t)(row + r) * N + col] = v;
            }
        }
    }
}

// ================= 128 x 384 pipelined bf16 GEMM (QKV projection) =================
// Grid (16,32)=512 blocks = exactly 2 full rounds. See R4 notes; unchanged.
#define STAGE_A3(L, T_, B_) load_lds16(Ag + (size_t)(L) * 64 * K + (size_t)(T_) * 64, \
                                       smA + (B_) * 8192 + (L) * 4096 + ldsW)
#define STAGE_B3(L, T_, B_) load_lds16(Bg + (size_t)((((L) & 1) * 2 + wnp) * 96 + ((L) >> 1) * 32 + rb) * K + (size_t)(T_) * 64, \
                                       smB + (B_) * 24576 + (L) * 4096 + ldsW)
#define READ_A3() do { const ushort* _ab = smA + cb * 8192 + aRow; \
    _Pragma("unroll") for (int i_ = 0; i_ < 4; ++i_) { \
        af[i_][0] = *(const short8*)(_ab + i_ * 1024 + pc0); \
        af[i_][1] = *(const short8*)(_ab + i_ * 1024 + pc1); } } while (0)
#define READ_B3(H) do { const ushort* _bb = smB + cb * 24576 + (H) * 8192 + bRow; \
    _Pragma("unroll") for (int j_ = 0; j_ < 2; ++j_) { \
        bfr[j_][0] = *(const short8*)(_bb + j_ * 1024 + pc0); \
        bfr[j_][1] = *(const short8*)(_bb + j_ * 1024 + pc1); } } while (0)
#define MFMA_P3(H) do { \
    _Pragma("unroll") for (int i_ = 0; i_ < 4; ++i_) \
    _Pragma("unroll") for (int j_ = 0; j_ < 2; ++j_) { \
        acc[i_][(H) * 2 + j_] = __builtin_amdgcn_mfma_f32_16x16x32_bf16( \
            af[i_][0], bfr[j_][0], acc[i_][(H) * 2 + j_], 0, 0, 0); \
        acc[i_][(H) * 2 + j_] = __builtin_amdgcn_mfma_f32_16x16x32_bf16( \
            af[i_][1], bfr[j_][1], acc[i_][(H) * 2 + j_], 0, 0, 0); } } while (0)

__global__ __launch_bounds__(512, 2) void gemm384(
    const ushort* __restrict__ A,   // [M][K] bf16
    const ushort* __restrict__ Bt,  // [N][K] bf16
    const float* __restrict__ bias, // [N]
    ushort* __restrict__ C,         // [M][N] bf16
    int M, int N, int K)
{
    __shared__ __align__(16) ushort sm[65536]; // A [0,16384), B [16384,65536)
    ushort* smA = sm;
    ushort* smB = sm + 16384;

    int t = threadIdx.x;
    int w = t >> 6, lane = t & 63;
    int lr = lane & 15, lh = lane >> 4;
    int wm_idx = w >> 2, wn_idx = w & 3;    // 2 x 4 wave grid, per-wave 64 x 96
    int m0 = blockIdx.y * 128, n0 = blockIdx.x * 384;

    int srow = t >> 3;                       // 0..63
    int scol = ((t & 7) ^ (srow & 7)) << 3;  // pre-swizzled source chunk
    const ushort* Ag = A + (size_t)(m0 + srow) * K + scol;
    const ushort* Bg = Bt + (size_t)n0 * K + scol;
    int wnp = srow >> 5;                     // B perm helpers
    int rb = srow & 31;
    int ldsW = w * 512;

    int pc0 = (lh ^ (lr & 7)) << 3;
    int pc1 = ((4 + lh) ^ (lr & 7)) << 3;
    int aRow = (wm_idx * 64 + lr) * 64;
    int bRow = (wn_idx * 32 + lr) * 64;

    f32x4 acc[4][6];
#pragma unroll
    for (int i = 0; i < 4; ++i)
#pragma unroll
        for (int j = 0; j < 6; ++j) acc[i][j] = (f32x4)0.0f;
    short8 af[4][2], bfr[2][2];

    int NT = K >> 6;

    STAGE_A3(0, 0, 0); STAGE_A3(1, 0, 0); STAGE_B3(0, 0, 0); STAGE_B3(1, 0, 0);
    STAGE_B3(2, 0, 0); STAGE_B3(3, 0, 0); STAGE_B3(4, 0, 0); STAGE_B3(5, 0, 0);
    WAITV(4);
    BARF();

    for (int T = 0; T < NT; ++T) {
        int cb = T & 1, nb = cb ^ 1;
        bool pf = (T + 1 < NT);
        // ---- P1: A x B-half0 ----
        READ_A3(); READ_B3(0);
        if (pf) { STAGE_A3(0, T + 1, nb); STAGE_A3(1, T + 1, nb); STAGE_B3(0, T + 1, nb); }
        BARF();
        PRIO1; MFMA_P3(0); PRIO0;
        if (pf) WAITV(5); else WAITV(2);
        BARF();
        // ---- P2: A x B-half1 (A cached) ----
        READ_B3(1);
        if (pf) { STAGE_B3(1, T + 1, nb); STAGE_B3(2, T + 1, nb); STAGE_B3(3, T + 1, nb); }
        BARF();
        PRIO1; MFMA_P3(1); PRIO0;
        if (pf) WAITV(6); else WAITV(0);
        BARF();
        // ---- P3: A x B-half2 ----
        READ_B3(2);
        if (pf) { STAGE_B3(4, T + 1, nb); STAGE_B3(5, T + 1, nb); }
        BARF();
        PRIO1; MFMA_P3(2); PRIO0;
        if (pf) WAITV(4);
        BARF();
    }

    float bv[6];
#pragma unroll
    for (int jj = 0; jj < 6; ++jj) bv[jj] = bias[n0 + wn_idx * 96 + jj * 16 + lr];
#pragma unroll
    for (int ii = 0; ii < 4; ++ii) {
        int row = m0 + wm_idx * 64 + ii * 16 + lh * 4;
#pragma unroll
        for (int jj = 0; jj < 6; ++jj) {
            int col = n0 + wn_idx * 96 + jj * 16 + lr;
#pragma unroll
            for (int r = 0; r < 4; ++r) {
                float v = acc[ii][jj][r] + bv[jj];
                C[(size_t)(row + r) * N + col] = f2bf(v);
            }
        }
    }
}

// ================= fused RoPE q/k + V transpose (1 launch) =================
__global__ void rope_v_fused(const ushort* __restrict__ qkv, const float2* __restrict__ tab,
                             ushort* __restrict__ Qb, ushort* __restrict__ Kb,
                             ushort* __restrict__ Vt) {
    __shared__ ushort tile[32][33];
    int blk = blockIdx.x;
    int t = threadIdx.x;
    if (blk < 32768) {
        // RoPE + cast + reshape q,k; Q pre-scaled by 1/sqrt(HD)
        int wv = blk * 4 + (t >> 6); // 0..131071
        int j = t & 63;
        int bs = wv >> 5;
        int rem = wv & 31;
        int which = rem >> 4;  // 0=q, 1=k
        int h = rem & 15;
        int s = bs & 2047;
        int b = bs >> 11;
        size_t src = (size_t)bs * QKV_LD + which * D_MODEL + h * HD;
        uint32_t pr = *(const uint32_t*)(qkv + src + 2 * j);
        float x1 = bf2f((ushort)(pr & 0xffff));
        float x2 = bf2f((ushort)(pr >> 16));
        float2 cspair = tab[(s << 6) + j];
        float cs = cspair.x, sn = cspair.y;
        float sc = which ? 1.0f : 0.08838834764831845f;
        float o1 = (x1 * cs - x2 * sn) * sc;
        float o2 = (x1 * sn + x2 * cs) * sc;
        ushort* dst = which ? Kb : Qb;
        size_t obase = ((size_t)(b * NH + h) * SEQ + s) * HD;
        dst[obase + j] = f2bf(o1);
        dst[obase + 64 + j] = f2bf(o2);
    } else {
        // V transpose -> Vt [bh][d=128][s=2048]; original grid (64,4,32)
        int i = blk - 32768;
        int bx = i & 63, by = (i >> 6) & 3, bz = i >> 8;
        int tx = t & 31, ty = t >> 5; // 32 x 8
        int s0 = bx * 32;
        int d0 = by * 32;
        int bh = bz;
        int b = bh >> 4, h = bh & 15;
        for (int k = 0; k < 4; ++k) {
            int s = s0 + ty + k * 8;
            tile[ty + k * 8][tx] = qkv[((size_t)(b * SEQ + s)) * QKV_LD + 2 * D_MODEL + h * HD + d0 + tx];
        }
        __syncthreads();
        for (int k = 0; k < 4; ++k) {
            int d = d0 + ty + k * 8;
            Vt[((size_t)bh * HD + d) * SEQ + s0 + tx] = tile[tx][ty + k * 8];
        }
    }
}

// ---------------- MFMA flash attention ----------------
// XCD-aware work swizzle: executing flat id f takes work wid=(f&7)*64+(f>>3)
// (bijective, 512%8==0) so all 16 q-tiles of each bh land on ONE XCD ->
// K/V per XCD = 4 bh x 1 MB = 4 MB = one L2; HBM K/V traffic ~256 MB -> ~32 MB.
__global__ __launch_bounds__(256) void attn_mfma(const ushort* __restrict__ Qb,
                                                 const ushort* __restrict__ Kb,
                                                 const ushort* __restrict__ Vt,
                                                 ushort* __restrict__ ctx) {
    __shared__ ushort smem[25600]; // Ks[0,8192) Vts[8192,16384) Ps[16384,25600)
    ushort* Ks = smem;          // [64][128], 16B chunks swizzled: c' = c ^ (row&15)
    ushort* Vts = smem + 8192;  // [128][64], 16B chunks swizzled: c' = c ^ (row&7)
    ushort* Ps = smem + 16384;  // [128][72] (pad 8 => 144B rows, 16B aligned)

    int t = threadIdx.x;
    int w = t >> 6, l = t & 63;
    int l31 = l & 31, g = l >> 5;
    int flat = blockIdx.y * 16 + blockIdx.x;    // launched id, 0..511
    int wid = (flat & 7) * 64 + (flat >> 3);    // work id, XCD-grouped by bh
    int q0 = (wid & 15) * 128;
    int bh = wid >> 4;
    int b = bh >> 4, h = bh & 15;

    int qrow = q0 + w * 32 + l31;
    const ushort* Qg = Qb + ((size_t)bh * SEQ + qrow) * HD;
    short8 qf[8];
#pragma unroll
    for (int kc = 0; kc < 8; kc++)
        qf[kc] = *(const short8*)(Qg + kc * 16 + g * 8);

    f32x16 O[4];
#pragma unroll
    for (int di = 0; di < 4; di++) O[di] = (f32x16)0.0f;
    float m_run = -INFINITY, l_run = 0.0f;

    const ushort* KgB = Kb + (size_t)bh * SEQ * HD;
    const ushort* VtB = Vt + (size_t)bh * HD * SEQ;

    for (int k0 = 0; k0 < SEQ; k0 += 64) {
        __syncthreads();
#pragma unroll
        for (int c2 = 0; c2 < 4; c2++) {
            int f = c2 * 256 + t;
            int r = f >> 4, c = f & 15;
            int cp = c ^ (r & 15);
            uint4 v = *(const uint4*)(KgB + (size_t)(k0 + r) * HD + c * 8);
            *(uint4*)(Ks + r * 128 + cp * 8) = v;
        }
#pragma unroll
        for (int c2 = 0; c2 < 4; c2++) {
            int f = c2 * 256 + t;
            int d = f >> 3, c = f & 7;
            int cp = c ^ (d & 7);
            uint4 v = *(const uint4*)(VtB + (size_t)d * SEQ + k0 + c * 8);
            *(uint4*)(Vts + d * 64 + cp * 8) = v;
        }
        __syncthreads();

        f32x16 St[2];
        St[0] = (f32x16)0.0f;
        St[1] = (f32x16)0.0f;
#pragma unroll
        for (int ki = 0; ki < 2; ki++) {
            int row = ki * 32 + l31;
#pragma unroll
            for (int kc = 0; kc < 8; kc++) {
                int cp = (kc * 2 + g) ^ (row & 15);
                short8 a = *(const short8*)(Ks + row * 128 + cp * 8);
                St[ki] = __builtin_amdgcn_mfma_f32_32x32x16_bf16(a, qf[kc], St[ki], 0, 0, 0);
            }
        }

        float mx = -INFINITY;
#pragma unroll
        for (int ki = 0; ki < 2; ki++)
#pragma unroll
            for (int r = 0; r < 16; r++) mx = fmaxf(mx, St[ki][r]);
        mx = fmaxf(mx, __shfl_xor(mx, 32));
        float mn = fmaxf(m_run, mx);
        float alpha = __expf(m_run - mn);
        m_run = mn;
        float psum = 0.0f;
#pragma unroll
        for (int ki = 0; ki < 2; ki++)
#pragma unroll
            for (int r = 0; r < 16; r++) {
                float p = __expf(St[ki][r] - mn);
                St[ki][r] = p;
                psum += p;
            }
        psum += __shfl_xor(psum, 32);
        l_run = l_run * alpha + psum;
#pragma unroll
        for (int di = 0; di < 4; di++)
#pragma unroll
            for (int r = 0; r < 16; r++) O[di][r] *= alpha;

        {
            int qloc = w * 32 + l31;
            ushort* Pr = Ps + qloc * 72;
#pragma unroll
            for (int ki = 0; ki < 2; ki++)
#pragma unroll
                for (int u = 0; u < 4; u++) {
                    ushort4 pk;
                    pk.x = f2bf(St[ki][4 * u + 0]);
                    pk.y = f2bf(St[ki][4 * u + 1]);
                    pk.z = f2bf(St[ki][4 * u + 2]);
                    pk.w = f2bf(St[ki][4 * u + 3]);
                    *(ushort4*)(Pr + ki * 32 + 8 * u + 4 * g) = pk;
                }
        }

        {
            int qloc = w * 32 + l31;
            short8 pb[4];
#pragma unroll
            for (int kc = 0; kc < 4; kc++)
                pb[kc] = *(const short8*)(Ps + qloc * 72 + kc * 16 + g * 8);
#pragma unroll
            for (int di = 0; di < 4; di++) {
                int d = di * 32 + l31;
#pragma unroll
                for (int kc = 0; kc < 4; kc++) {
                    int cp = (kc * 2 + g) ^ (d & 7);
                    short8 va = *(const short8*)(Vts + d * 64 + cp * 8);
                    O[di] = __builtin_amdgcn_mfma_f32_32x32x16_bf16(va, pb[kc], O[di], 0, 0, 0);
                }
            }
        }
    }

    __syncthreads();
    float inv = 1.0f / l_run;
    ushort* ob = smem; // [128][128] rows = block-local q
    {
        int qloc = w * 32 + l31;
        ushort* orow = ob + qloc * 128;
#pragma unroll
        for (int di = 0; di < 4; di++)
#pragma unroll
            for (int u = 0; u < 4; u++) {
                ushort4 pk;
                pk.x = f2bf(O[di][4 * u + 0] * inv);
                pk.y = f2bf(O[di][4 * u + 1] * inv);
                pk.z = f2bf(O[di][4 * u + 2] * inv);
                pk.w = f2bf(O[di][4 * u + 3] * inv);
                *(ushort4*)(orow + di * 32 + 8 * u + 4 * g) = pk;
            }
    }
#pragma unroll
    for (int p = 0; p < 8; p++) {
        int qloc = w * 32 + p * 4 + (l >> 4);
        int c16 = l & 15;
        uint4 v = *(const uint4*)(ob + qloc * 128 + c16 * 8);
        size_t tok = (size_t)b * SEQ + q0 + qloc;
        *(uint4*)(ctx + tok * D_MODEL + h * HD + c16 * 8) = v;
    }
}

extern "C" void kernel_launch(void* const* d_in, const int* in_sizes, int n_in,
                              void* d_out, int out_size, void* d_ws, size_t ws_size,
                              hipStream_t stream) {
    const float* x    = (const float*)d_in[0];
    const float* Wqkv = (const float*)d_in[1];
    const float* bqkv = (const float*)d_in[2];
    const float* Wo   = (const float*)d_in[3];
    const float* bo   = (const float*)d_in[4];
    float* out = (float*)d_out;

    char* ws = (char*)d_ws;
    ushort* x_bf   = (ushort*)(ws);                  // 16 MB [0,16M)
    ushort* wqkvT  = (ushort*)(ws + 16777216);       // 24 MB
    ushort* woT    = (ushort*)(ws + 41943040);       //  8 MB
    ushort* qkv_bf = (ushort*)(ws + 50331648);       // 48 MB: [4096][6144] bf16
    ushort* Qb     = (ushort*)(ws + 100663296);      // 16 MB: [32][2048][128] bf16
    ushort* Kb     = (ushort*)(ws + 117440512);      // 16 MB
    ushort* VtG    = (ushort*)(ws + 134217728);      // 16 MB: [32][128][2048] bf16
    ushort* ctx    = (ushort*)(ws + 150994944);      // 16 MB -> total 160 MB
    // rope table overlaps ctx region (1 MB): consumed by rope_v_fused BEFORE attn writes ctx.
    float2* rtab   = (float2*)(ws + 150994944);

    // 1) fused prep: rope table + x->bf16 + Wqkv^T + Wo^T
    prep_fused<<<25088, 256, 0, stream>>>(x, x_bf, Wqkv, wqkvT, Wo, woT, rtab);
    // 2) qkv = x @ Wqkv + bqkv -> bf16 (128x384, 512 blocks = 2 exact rounds)
    gemm384<<<dim3(16, 32), 512, 0, stream>>>(x_bf, wqkvT, bqkv, qkv_bf, 4096, 6144, 2048);
    // 3) fused RoPE q/k + V transpose
    rope_v_fused<<<40960, 256, 0, stream>>>(qkv_bf, rtab, Qb, Kb, VtG);
    // 4) MFMA flash attention -> ctx bf16 (XCD-swizzled)
    attn_mfma<<<dim3(16, 32), 256, 0, stream>>>(Qb, Kb, VtG, ctx);
    // 5) out = ctx @ Wo + bo (256x128, 256 blocks = full machine)
    gemm256<float, 1><<<dim3(16, 16), 512, 0, stream>>>(ctx, woT, bo, out, 4096, 2048, 2048);
}